// Round 9
// baseline (1630.201 us; speedup 1.0000x reference)
//
#include <hip/hip_runtime.h>

typedef unsigned int u32;
typedef unsigned short u16;
typedef unsigned long long u64;
typedef short s8 __attribute__((ext_vector_type(8)));   // 8 x bf16 (as i16)
typedef float f4 __attribute__((ext_vector_type(4)));
typedef u32 v4 __attribute__((ext_vector_type(4)));     // 16B asm load payload

#define B_SZ   1024
#define H_SZ   512
#define G4     2048
#define NSTEPS 64

// ws layout (bytes)
#define WS_XE     0u          // [64][1024][16] bf16 = 2097152
#define WS_W0C    2097152u    // [2048][32]  bf16    = 131072
#define WS_WIH1   2228224u    // [2048][512] bf16    = 2097152
#define WS_WHH0   4325376u    // [2048][512] bf16    = 2097152
#define WS_WHH1   6422528u    // [2048][512] bf16    = 2097152
#define WS_H0T    8519680u    // TILED [64 rblk][16 kblk][512] u16 = 1048576
#define WS_H1T    9568256u    // same = 1048576
#define WS_YPART  10616832u   // [32 js][1024 rows] f32 = 131072
#define WS_FLAGS  10747904u   // [8][32] u32 = 1024
#define WS_NEEDED 10748928u

// h TILED: tile(rblk=r>>4, kblk=k>>5) 1KB at (rblk*16+kblk)*1024;
// inner byte lane*16, lane=(r&15)+((k>>3)&3)*16 == MFMA A-frag map.

// LDS layout (bytes); weight row stride 1040 (520 bf16)
#define SLOT0   0        // 64 x 1040 = 66560
#define SLOT1   66560    // 64 x 1040 (phase B: overlaid by ypl[32][132] f32)
#define W0CL    133120   // 64 x 64
#define HST     137216   // u16[128][16] = 4096
#define YFIN    141312   // f32[128]
#define LDS_TOTAL 141824

__device__ __forceinline__ float bf2f(short s) {
  u32 u = ((u32)(u16)s) << 16; float f; __builtin_memcpy(&f, &u, 4); return f;
}
__device__ __forceinline__ short f2bf(float f) {
  u32 u; __builtin_memcpy(&u, &f, 4);
  u = (u + 0x7fffu + ((u >> 16) & 1u)) >> 16; return (short)u;
}
__device__ __forceinline__ float sigm(float x) { return 1.f / (1.f + __expf(-x)); }
__device__ __forceinline__ float tanh_(float x) {
  float ax = fminf(fabsf(x), 15.f);
  float e = __expf(2.f * ax);
  float r = (e - 1.f) / (e + 1.f);
  return x < 0.f ? -r : r;
}

__device__ __forceinline__ u64 ald(const u64* p) {
  return __hip_atomic_load(p, __ATOMIC_RELAXED, __HIP_MEMORY_SCOPE_AGENT);
}
__device__ __forceinline__ void ast(u64* p, u64 v) {
  __hip_atomic_store(p, v, __ATOMIC_RELAXED, __HIP_MEMORY_SCOPE_AGENT);
}
__device__ __forceinline__ u32 ald32(const u32* p) {
  return __hip_atomic_load(p, __ATOMIC_RELAXED, __HIP_MEMORY_SCOPE_AGENT);
}
__device__ __forceinline__ void ast32(u32* p, u32 v) {
  __hip_atomic_store(p, v, __ATOMIC_RELAXED, __HIP_MEMORY_SCOPE_AGENT);
}

// device-scope 16B load (sc1: L2-bypass, L3-coherent); async until WAITV
#define LOADX4(dst, ptr, IMM) \
  asm volatile("global_load_dwordx4 %0, %1, off offset:" #IMM " sc1" : "=v"(dst) : "v"(ptr))
#define WAITV(N) do { \
  asm volatile("s_waitcnt vmcnt(" #N ")" ::: "memory"); \
  __builtin_amdgcn_sched_barrier(0); } while (0)

// one k-group = 4 consecutive 1KB tiles of one row-block
#define IS4(r0,r1,r2,r3,P) do { \
  LOADX4(r0, P, 0); LOADX4(r1, P, 1024); LOADX4(r2, P, 2048); LOADX4(r3, P, 3072); } while (0)

union vv { v4 u; s8 s; };
__device__ __forceinline__ s8 as_s8(v4 x) { vv t; t.u = x; return t.s; }
union uab { u64 q[2]; s8 v; };
union vf4 { v4 u; float f[4]; };
union f4u { float f[4]; u64 q[2]; };

// ---------------- prep kernels ----------------
__global__ void prep_pack(const float* __restrict__ Wih0, const float* __restrict__ Whh0,
                          const float* __restrict__ Wih1, const float* __restrict__ Whh1,
                          u16* __restrict__ W0C, u16* __restrict__ WIH1p,
                          u16* __restrict__ WHH0p, u16* __restrict__ WHH1p) {
  int stride = gridDim.x * blockDim.x;
  int i0 = blockIdx.x * blockDim.x + threadIdx.x;
  for (int idx = i0; idx < G4 * 32; idx += stride) {
    int n = idx >> 5, k = idx & 31;
    W0C[idx] = (k < 9) ? (u16)f2bf(Wih0[n * 9 + k]) : (u16)0;
  }
  for (int idx = i0; idx < G4 * 512; idx += stride) {
    WIH1p[idx] = (u16)f2bf(Wih1[idx]);
    WHH0p[idx] = (u16)f2bf(Whh0[idx]);
    WHH1p[idx] = (u16)f2bf(Whh1[idx]);
  }
}

__global__ void prep_xe(const float* __restrict__ xf, const float* __restrict__ z,
                        const float* __restrict__ Wz, const float* __restrict__ bz,
                        const float* __restrict__ bproj, u16* __restrict__ xe) {
  int idx = blockIdx.x * blockDim.x + threadIdx.x;
  if (idx >= NSTEPS * B_SZ) return;
  int t = idx >> 10, b = idx & 1023;
  float zb[9];
#pragma unroll
  for (int i = 0; i < 9; i++) {
    float s = bz[i];
#pragma unroll
    for (int d = 0; d < 16; d++) s += z[b * 16 + d] * Wz[i * 16 + d];
    zb[i] = s;
  }
  __align__(16) u16 o[16];
  // t>0: prev_y = bpj + wproj.h1; bpj folded here, wproj.h1 via rank-1 yfin
  o[0] = (u16)f2bf(zb[0] + (t > 0 ? bproj[0] : 0.f));
#pragma unroll
  for (int e = 0; e < 8; e++) o[1 + e] = (u16)f2bf(xf[b * 512 + t * 8 + e] + zb[1 + e]);
#pragma unroll
  for (int k = 9; k < 16; k++) o[k] = 0;
  uint4* dst = (uint4*)(xe + (size_t)idx * 16);
  dst[0] = *(const uint4*)&o[0];
  dst[1] = *(const uint4*)&o[8];
}

// initial h -> TILED single-slot buffers
__global__ void prep_state(const float* __restrict__ h0in, u16* __restrict__ h0t,
                           u16* __restrict__ h1t, u32* __restrict__ flags) {
  int i = blockIdx.x * blockDim.x + threadIdx.x;
  if (i < B_SZ * H_SZ) {
    int r = i >> 9, k = i & 511;
    int ti = ((r >> 4) * 16 + (k >> 5)) * 512
           + ((r & 15) + (((k >> 3) & 3) << 4)) * 8 + (k & 7);
    h0t[ti] = (u16)f2bf(h0in[i]);
    h1t[ti] = (u16)f2bf(h0in[524288 + i]);
  }
  if (i < 256) flags[i] = 0;
}

// ---------------- main persistent kernel ----------------
struct MainParams {
  const float* y0; const float* c0;
  const float* bih0; const float* bhh0; const float* bih1; const float* bhh1;
  const float* wih0raw; const float* wproj; const float* bproj;
  const u16* xe; const u16* w0c; const u16* wih1; const u16* whh0; const u16* whh1;
  u64* h0t; u64* h1t; float* ypart; u32* flags; float* out;
};

__device__ __forceinline__ f4 MFMA_(s8 a, s8 b, f4 c) {
  return __builtin_amdgcn_mfma_f32_16x16x32_bf16(a, b, c, 0, 0, 0);
}

// dual consume: A regs (4 k-chunks of one row-block) -> accQ(slot0) + accP(slot1)
__device__ __forceinline__ void cons_d(v4 A0, v4 A1, v4 A2, v4 A3, int hO,
    const char* bq0, const char* bq1, const char* bq2, const char* bq3,
    const char* bp0, const char* bp1, const char* bp2, const char* bp3,
    f4 accQ[4], f4 accP[4]) {
#pragma unroll
  for (int kc = 0; kc < 4; kc++) {
    s8 a = as_s8(kc == 0 ? A0 : kc == 1 ? A1 : kc == 2 ? A2 : A3);
    int o = hO + kc * 64;
    accQ[0] = MFMA_(a, *(const s8*)(bq0 + o), accQ[0]);
    accQ[1] = MFMA_(a, *(const s8*)(bq1 + o), accQ[1]);
    accQ[2] = MFMA_(a, *(const s8*)(bq2 + o), accQ[2]);
    accQ[3] = MFMA_(a, *(const s8*)(bq3 + o), accQ[3]);
    accP[0] = MFMA_(a, *(const s8*)(bp0 + o), accP[0]);
    accP[1] = MFMA_(a, *(const s8*)(bp1 + o), accP[1]);
    accP[2] = MFMA_(a, *(const s8*)(bp2 + o), accP[2]);
    accP[3] = MFMA_(a, *(const s8*)(bp3 + o), accP[3]);
  }
}
// single consume -> accQ only
__device__ __forceinline__ void cons_s(v4 A0, v4 A1, v4 A2, v4 A3, int hO,
    const char* bq0, const char* bq1, const char* bq2, const char* bq3, f4 accQ[4]) {
#pragma unroll
  for (int kc = 0; kc < 4; kc++) {
    s8 a = as_s8(kc == 0 ? A0 : kc == 1 ? A1 : kc == 2 ? A2 : A3);
    int o = hO + kc * 64;
    accQ[0] = MFMA_(a, *(const s8*)(bq0 + o), accQ[0]);
    accQ[1] = MFMA_(a, *(const s8*)(bq1 + o), accQ[1]);
    accQ[2] = MFMA_(a, *(const s8*)(bq2 + o), accQ[2]);
    accQ[3] = MFMA_(a, *(const s8*)(bq3 + o), accQ[3]);
  }
}

__device__ __forceinline__ void barrier_wait(u32* slots, int js16, int tid, u32 target) {
  asm volatile("s_waitcnt vmcnt(0)" ::: "memory");
  __syncthreads();
  if (tid == 0) ast32(&slots[js16], target);
  if (tid < 32) {
    int spins = 0;
    while (ald32(&slots[tid]) < target) {
      __builtin_amdgcn_s_sleep(1);
      if (++spins > (1 << 18)) break;   // fail-safe: never hang
    }
  }
  __syncthreads();
}

// stage both weight slots from global (cacheable, L2-hot after first step)
__device__ __forceinline__ void stage2(char* lds, int js16, int tid,
                                       const u16* W0, const u16* W1) {
  int m = tid >> 8, l = (tid >> 2) & 63, q = tid & 3;
  int ng = (l >> 4) * 512 + js16 * 16 + (l & 15);
  const uint4* s4 = (const uint4*)((m ? W1 : W0) + (size_t)ng * 512 + q * 128);
  uint4* d4 = (uint4*)(lds + (m ? SLOT1 : SLOT0) + l * 1040 + q * 256);
#pragma unroll
  for (int i = 0; i < 16; i++) d4[i] = s4[i];
}
__device__ __forceinline__ void stage1(char* lds, int js16, int tid, const u16* W0) {
  if (tid >= 256) return;
  int l = tid >> 2, q = tid & 3;
  int ng = (l >> 4) * 512 + js16 * 16 + (l & 15);
  const uint4* s4 = (const uint4*)(W0 + (size_t)ng * 512 + q * 128);
  uint4* d4 = (uint4*)(lds + SLOT0 + l * 1040 + q * 256);
#pragma unroll
  for (int i = 0; i < 16; i++) d4[i] = s4[i];
}

// prologue-only K=512 gemm (atomic loads, runs twice total)
__device__ __forceinline__ void proto_gemm(const u64* ht, int rblk, int lane,
    const char* b0, const char* b1, const char* b2, const char* b3, f4 acc[4]) {
#pragma unroll
  for (int kc = 0; kc < 16; kc++) {
    uab a;
    int base = rblk * 2048 + kc * 128 + lane * 2;
    a.q[0] = ald(ht + base); a.q[1] = ald(ht + base + 1);
    int o = kc * 64;
    acc[0] = MFMA_(a.v, *(const s8*)(b0 + o), acc[0]);
    acc[1] = MFMA_(a.v, *(const s8*)(b1 + o), acc[1]);
    acc[2] = MFMA_(a.v, *(const s8*)(b2 + o), acc[2]);
    acc[3] = MFMA_(a.v, *(const s8*)(b3 + o), acc[3]);
  }
}

__global__ __launch_bounds__(512, 2) void lstm_main(MainParams p) {
  extern __shared__ char lds[];
  u16* hst = (u16*)(lds + HST);
  float* yfin = (float*)(lds + YFIN);

  const int bx = blockIdx.x, chunk = bx >> 5, js16 = bx & 31;
  const int tid = threadIdx.x, lane = tid & 63, wid = tid >> 6;
  const int pp = lane & 15, grp = lane >> 4;
  const int rblk = chunk * 8 + wid;
  const int abase = rblk * 16384 + lane * 16;   // tiled h byte offset
  const int j = js16 * 16 + pp;

  { // static w0c stage
    if (tid < 256) {
      int l = tid >> 2, q = tid & 3;
      int ng = (l >> 4) * 512 + js16 * 16 + (l & 15);
      *(uint4*)(lds + W0CL + l * 64 + q * 16) =
          *(const uint4*)(p.w0c + (size_t)ng * 32 + q * 8);
    }
    stage2(lds, js16, tid, p.whh0, p.whh1);   // prologue: slot0=Whh0, slot1=Whh1
  }

  // lane-static params
  float bias0[4], bias1[4], uc0[4];
#pragma unroll
  for (int nt = 0; nt < 4; nt++) {
    int ng = nt * 512 + j;
    bias0[nt] = p.bih0[ng] + p.bhh0[ng];
    bias1[nt] = p.bih1[ng] + p.bhh1[ng];
    uc0[nt] = p.wih0raw[ng * 9];          // W_ih0[:,0]
  }
  float wpj = p.wproj[j];
  float bpj = p.bproj[0];

  // cell state: 4 rows (C/D rows of this lane) x 1 j, both layers
  const int rbase = chunk * 128 + wid * 16 + grp * 4;
  f4 c0r, c1r;
#pragma unroll
  for (int ri = 0; ri < 4; ri++) {
    c0r[ri] = p.c0[(rbase + ri) * 512 + j];
    c1r[ri] = p.c0[524288 + (rbase + ri) * 512 + j];
  }

  u32* flagc = p.flags + chunk * 32;

  // LDS B pointers (per n-tile = gate)
  const char* bq0 = lds + SLOT0 + (0 * 16 + pp) * 1040 + grp * 16;
  const char* bq1 = lds + SLOT0 + (1 * 16 + pp) * 1040 + grp * 16;
  const char* bq2 = lds + SLOT0 + (2 * 16 + pp) * 1040 + grp * 16;
  const char* bq3 = lds + SLOT0 + (3 * 16 + pp) * 1040 + grp * 16;
  const char* bp0 = lds + SLOT1 + (0 * 16 + pp) * 1040 + grp * 16;
  const char* bp1 = lds + SLOT1 + (1 * 16 + pp) * 1040 + grp * 16;
  const char* bp2 = lds + SLOT1 + (2 * 16 + pp) * 1040 + grp * 16;
  const char* bp3 = lds + SLOT1 + (3 * 16 + pp) * 1040 + grp * 16;
  const char* bc0 = lds + W0CL + (0 * 16 + pp) * 64 + grp * 16;
  const char* bc1 = lds + W0CL + (1 * 16 + pp) * 64 + grp * 16;
  const char* bc2 = lds + W0CL + (2 * 16 + pp) * 64 + grp * 16;
  const char* bc3 = lds + W0CL + (3 * 16 + pp) * 64 + grp * 16;

  const int rot = js16 & 3;
  const int g0 = ((rot + 0) & 3) * 4096, g1 = ((rot + 1) & 3) * 4096;
  const int g2 = ((rot + 2) & 3) * 4096, g3 = ((rot + 3) & 3) * 4096;
  const int o0 = g0 >> 4, o1 = g1 >> 4, o2 = g2 >> 4, o3 = g3 >> 4;

  __syncthreads();

  f4 accP[4] = {{0,0,0,0},{0,0,0,0},{0,0,0,0},{0,0,0,0}};
  f4 accQ[4] = {{0,0,0,0},{0,0,0,0},{0,0,0,0},{0,0,0,0}};
  u32 tgt = 1;

  // ===== prologue: gates0(0)=Whh0 h0(-1)+chunk0(y0); carry accQ=Whh1 h1(-1) =====
  proto_gemm(p.h0t, rblk, lane, bq0, bq1, bq2, bq3, accP);
  { // chunk0 t=0 with y0
    s8 a = {0,0,0,0,0,0,0,0};
    int arow = chunk * 128 + wid * 16 + pp;
    if (grp < 2) {
      a = *(const s8*)((const char*)p.xe + arow * 32 + grp * 16);
      if (grp == 0) a[0] = f2bf(bf2f(a[0]) + p.y0[arow]);
    }
    accP[0] = MFMA_(a, *(const s8*)bc0, accP[0]);
    accP[1] = MFMA_(a, *(const s8*)bc1, accP[1]);
    accP[2] = MFMA_(a, *(const s8*)bc2, accP[2]);
    accP[3] = MFMA_(a, *(const s8*)bc3, accP[3]);
  }
  { // cell0 -> h0(0) into hst
#pragma unroll
    for (int ri = 0; ri < 4; ri++) {
      float iv = accP[0][ri] + bias0[0], fv = accP[1][ri] + bias0[1];
      float gv = accP[2][ri] + bias0[2], ov = accP[3][ri] + bias0[3];
      float c2 = sigm(fv) * c0r[ri] + sigm(iv) * tanh_(gv);
      float hv = sigm(ov) * tanh_(c2);
      c0r[ri] = c2;
      hst[(wid * 16 + grp * 4 + ri) * 16 + pp] = (u16)f2bf(hv);
    }
  }
  proto_gemm(p.h1t, rblk, lane, bp0, bp1, bp2, bp3, accQ);  // Whh1 h1(-1)
  barrier_wait(flagc, js16, tid, tgt++);   // all done reading initial h
  if (tid < 256) {   // store h0(0) tiled
    int rl = tid & 127, half = tid >> 7;
    const u64* src = (const u64*)(hst + rl * 16 + half * 8);
    int tile = (chunk * 8 + (rl >> 4)) * 16 + (js16 >> 1);
    int slot = (rl & 15) + ((js16 & 1) * 2 + half) * 16;
    u64* dst = p.h0t + tile * 128 + slot * 2;
    ast(dst, src[0]); ast(dst + 1, src[1]);
  }
  barrier_wait(flagc, js16, tid, tgt++);   // h0(0) visible
#pragma unroll
  for (int q = 0; q < 4; q++) accP[q] = (f4){0, 0, 0, 0};

  v4 A0, A1, A2, A3, C0, C1, C2, C3;

  for (int t = 0; t < NSTEPS; t++) {
    // ===== phase A: stage(Wih1,Whh0); read h0(t) -> accQ+=Wih1 h0, accP+=Whh0 h0 =====
    {
      stage2(lds, js16, tid, p.wih1, p.whh0);
      __syncthreads();
      __builtin_amdgcn_sched_barrier(0);
      const char* pa = (const char*)p.h0t + abase;
      IS4(A0, A1, A2, A3, pa + g0);
      IS4(C0, C1, C2, C3, pa + g1);
      WAITV(4);
      cons_d(A0, A1, A2, A3, o0, bq0, bq1, bq2, bq3, bp0, bp1, bp2, bp3, accQ, accP);
      IS4(A0, A1, A2, A3, pa + g2);
      WAITV(4);
      cons_d(C0, C1, C2, C3, o1, bq0, bq1, bq2, bq3, bp0, bp1, bp2, bp3, accQ, accP);
      IS4(C0, C1, C2, C3, pa + g3);
      WAITV(4);
      cons_d(A0, A1, A2, A3, o2, bq0, bq1, bq2, bq3, bp0, bp1, bp2, bp3, accQ, accP);
      WAITV(0);
      cons_d(C0, C1, C2, C3, o3, bq0, bq1, bq2, bq3, bp0, bp1, bp2, bp3, accQ, accP);

      // cell1 -> h1(t), y-partials
      float py[4];
#pragma unroll
      for (int ri = 0; ri < 4; ri++) {
        float iv = accQ[0][ri] + bias1[0], fv = accQ[1][ri] + bias1[1];
        float gv = accQ[2][ri] + bias1[2], ov = accQ[3][ri] + bias1[3];
        float c2 = sigm(fv) * c1r[ri] + sigm(iv) * tanh_(gv);
        float hv = sigm(ov) * tanh_(c2);
        c1r[ri] = c2;
        hst[(wid * 16 + grp * 4 + ri) * 16 + pp] = (u16)f2bf(hv);
        py[ri] = hv * wpj;
      }
#pragma unroll
      for (int m = 1; m < 16; m <<= 1)
#pragma unroll
        for (int ri = 0; ri < 4; ri++) py[ri] += __shfl_xor(py[ri], m);
      if (pp == 0) {   // contiguous 16B per lane-group: ypart[js16][rows]
        f4u u; u.f[0] = py[0]; u.f[1] = py[1]; u.f[2] = py[2]; u.f[3] = py[3];
        u64* dst = (u64*)((char*)p.ypart + js16 * 4096 + (size_t)rbase * 4);
        ast(dst, u.q[0]); ast(dst + 1, u.q[1]);
      }
      __syncthreads();
      if (tid < 256) {   // h1(t) tiled store
        int rl = tid & 127, half = tid >> 7;
        const u64* src = (const u64*)(hst + rl * 16 + half * 8);
        int tile = (chunk * 8 + (rl >> 4)) * 16 + (js16 >> 1);
        int slot = (rl & 15) + ((js16 & 1) * 2 + half) * 16;
        u64* dst = p.h1t + tile * 128 + slot * 2;
        ast(dst, src[0]); ast(dst + 1, src[1]);
      }
      barrier_wait(flagc, js16, tid, tgt++);
#pragma unroll
      for (int q = 0; q < 4; q++) accQ[q] = (f4){0, 0, 0, 0};
    }

    // ===== phase B: y-reduce; stage(Whh1); accQ=Whh1 h1(t); accP += uc0*y + chunk0 =====
    {
      // issue y-partial loads (32B per thread, contiguous runs)
      v4 Y0, Y1;
      {
        int run = tid >> 4, off = tid & 15;
        const char* yq = (const char*)p.ypart + run * 4096
                       + (size_t)(chunk * 128 + off * 8) * 4;
        LOADX4(Y0, yq, 0);
        LOADX4(Y1, yq, 16);
      }
      stage1(lds, js16, tid, p.whh1);   // slot0 = Whh1 (compiler-tracked loads)
      WAITV(0);                          // drain YP + staging
      { // deposit to padded LDS ypl[32][132] (overlaid on SLOT1)
        int run = tid >> 4, off = tid & 15;
        char* d = lds + SLOT1 + run * 528 + off * 32;
        vf4 w0; w0.u = Y0; vf4 w1; w1.u = Y1;
        *(float4*)d = *(float4*)&w0;
        *(float4*)(d + 16) = *(float4*)&w1;
      }
      __syncthreads();
      if (tid < 128) {
        float s = 0.f;
#pragma unroll
        for (int jsv = 0; jsv < 32; jsv++)
          s += *(const float*)(lds + SLOT1 + jsv * 528 + tid * 4);
        yfin[tid] = s;
        if (js16 == 0) p.out[(chunk * 128 + tid) * 64 + t] = s + bpj;
      }
      __syncthreads();
      __builtin_amdgcn_sched_barrier(0);

      const char* pb = (const char*)p.h1t + abase;
      IS4(A0, A1, A2, A3, pb + g0);
      IS4(C0, C1, C2, C3, pb + g1);
      WAITV(4);
      cons_s(A0, A1, A2, A3, o0, bq0, bq1, bq2, bq3, accQ);
      IS4(A0, A1, A2, A3, pb + g2);
      WAITV(4);
      cons_s(C0, C1, C2, C3, o1, bq0, bq1, bq2, bq3, accQ);
      IS4(C0, C1, C2, C3, pb + g3);
      WAITV(4);
      cons_s(A0, A1, A2, A3, o2, bq0, bq1, bq2, bq3, accQ);
      WAITV(0);
      cons_s(C0, C1, C2, C3, o3, bq0, bq1, bq2, bq3, accQ);

      // rank-1: gates0(t+1) += wih0[:,0] * y(t)
      f4 yf;
#pragma unroll
      for (int ri = 0; ri < 4; ri++) yf[ri] = yfin[wid * 16 + grp * 4 + ri];
#pragma unroll
      for (int nt = 0; nt < 4; nt++)
#pragma unroll
        for (int ri = 0; ri < 4; ri++) accP[nt][ri] += uc0[nt] * yf[ri];

      { // chunk0(t+1): exo+z(+bpj) const part
        int tn = (t < 63) ? t + 1 : 63;
        s8 a = {0,0,0,0,0,0,0,0};
        if (grp < 2) {
          int arow = chunk * 128 + wid * 16 + pp;
          a = *(const s8*)((const char*)p.xe + (size_t)tn * 32768 + arow * 32 + grp * 16);
        }
        accP[0] = MFMA_(a, *(const s8*)bc0, accP[0]);
        accP[1] = MFMA_(a, *(const s8*)bc1, accP[1]);
        accP[2] = MFMA_(a, *(const s8*)bc2, accP[2]);
        accP[3] = MFMA_(a, *(const s8*)bc3, accP[3]);
      }
      // cell0 -> h0(t+1)
#pragma unroll
      for (int ri = 0; ri < 4; ri++) {
        float iv = accP[0][ri] + bias0[0], fv = accP[1][ri] + bias0[1];
        float gv = accP[2][ri] + bias0[2], ov = accP[3][ri] + bias0[3];
        float c2 = sigm(fv) * c0r[ri] + sigm(iv) * tanh_(gv);
        float hv = sigm(ov) * tanh_(c2);
        c0r[ri] = c2;
        hst[(wid * 16 + grp * 4 + ri) * 16 + pp] = (u16)f2bf(hv);
      }
      __syncthreads();
      if (tid < 256) {   // h0(t+1) tiled store
        int rl = tid & 127, half = tid >> 7;
        const u64* src = (const u64*)(hst + rl * 16 + half * 8);
        int tile = (chunk * 8 + (rl >> 4)) * 16 + (js16 >> 1);
        int slot = (rl & 15) + ((js16 & 1) * 2 + half) * 16;
        u64* dst = p.h0t + tile * 128 + slot * 2;
        ast(dst, src[0]); ast(dst + 1, src[1]);
      }
      barrier_wait(flagc, js16, tid, tgt++);
#pragma unroll
      for (int q = 0; q < 4; q++) accP[q] = (f4){0, 0, 0, 0};
    }
  }
}

extern "C" void kernel_launch(void* const* d_in, const int* in_sizes, int n_in,
                              void* d_out, int out_size, void* d_ws, size_t ws_size,
                              hipStream_t stream) {
  const float* y0   = (const float*)d_in[0];
  const float* xf   = (const float*)d_in[1];
  const float* h0   = (const float*)d_in[2];
  const float* c0   = (const float*)d_in[3];
  const float* z    = (const float*)d_in[4];
  const float* Wih0 = (const float*)d_in[5];
  const float* Whh0 = (const float*)d_in[6];
  const float* bih0 = (const float*)d_in[7];
  const float* bhh0 = (const float*)d_in[8];
  const float* Wih1 = (const float*)d_in[9];
  const float* Whh1 = (const float*)d_in[10];
  const float* bih1 = (const float*)d_in[11];
  const float* bhh1 = (const float*)d_in[12];
  const float* Wpr  = (const float*)d_in[13];
  const float* bpr  = (const float*)d_in[14];
  const float* Wz   = (const float*)d_in[15];
  const float* bz   = (const float*)d_in[16];

  if (ws_size < WS_NEEDED) return;
  char* ws = (char*)d_ws;
  u16* xe    = (u16*)(ws + WS_XE);
  u16* w0c   = (u16*)(ws + WS_W0C);
  u16* wih1  = (u16*)(ws + WS_WIH1);
  u16* whh0  = (u16*)(ws + WS_WHH0);
  u16* whh1  = (u16*)(ws + WS_WHH1);
  u64* h0t   = (u64*)(ws + WS_H0T);
  u64* h1t   = (u64*)(ws + WS_H1T);
  float* ypart = (float*)(ws + WS_YPART);
  u32* flags = (u32*)(ws + WS_FLAGS);

  prep_pack<<<1024, 256, 0, stream>>>(Wih0, Whh0, Wih1, Whh1, w0c, wih1, whh0, whh1);
  prep_xe<<<256, 256, 0, stream>>>(xf, z, Wz, bz, bpr, xe);
  prep_state<<<2048, 256, 0, stream>>>(h0, (u16*)h0t, (u16*)h1t, flags);

  MainParams prm;
  prm.y0 = y0; prm.c0 = c0;
  prm.bih0 = bih0; prm.bhh0 = bhh0; prm.bih1 = bih1; prm.bhh1 = bhh1;
  prm.wih0raw = Wih0; prm.wproj = Wpr; prm.bproj = bpr;
  prm.xe = xe; prm.w0c = w0c; prm.wih1 = wih1; prm.whh0 = whh0; prm.whh1 = whh1;
  prm.h0t = h0t; prm.h1t = h1t; prm.ypart = ypart; prm.flags = flags;
  prm.out = (float*)d_out;

  hipFuncSetAttribute((const void*)lstm_main, hipFuncAttributeMaxDynamicSharedMemorySize, LDS_TOTAL);
  void* args[] = { &prm };
  hipLaunchCooperativeKernel((void*)lstm_main, dim3(256), dim3(512), args, LDS_TOTAL, stream);
}

// Round 11
// 1496.881 us; speedup vs baseline: 1.0891x; 1.0891x over previous
//
#include <hip/hip_runtime.h>

typedef unsigned int u32;
typedef unsigned short u16;
typedef unsigned long long u64;
typedef short s8 __attribute__((ext_vector_type(8)));   // 8 x bf16 (as i16)
typedef float f4 __attribute__((ext_vector_type(4)));
typedef u32 v4 __attribute__((ext_vector_type(4)));     // 16B asm load payload

#define B_SZ   1024
#define H_SZ   512
#define G4     2048
#define NSTEPS 64

// ws layout (bytes)
#define WS_XE     0u          // [64][1024][16] bf16  = 2097152
#define WS_W0C    2097152u    // [2048][32]  bf16     = 131072
#define WS_WIH1   2228224u    // [2048][512] bf16     = 2097152
#define WS_WHH0   4325376u    // [2048][512] bf16     = 2097152
#define WS_WHH1   6422528u    // [2048][512] bf16     = 2097152
#define WS_UP     8519680u    // [2048][512] bf16     = 2097152  (U = wih0[:,0] x wproj)
#define WS_H0S    10616832u   // [2][TILED 1024x512] bf16 = 2097152
#define WS_H1S    12713984u   // [2][TILED 1024x512] bf16 = 2097152
#define WS_YPART  14811136u   // [64 js][1024 rows] f32 = 262144 (single-buffered)
#define WS_FLAGS  15335424u   // [4][64] u32          = 1024
#define WS_NEEDED 15336448u

// h TILED layout: tile(rblk=r>>4, kblk=k>>5) = 1KB at rblk*16384 + kblk*1024;
// inner byte = lane*16, lane = (r&15) + ((k>>3)&3)*16  == MFMA A-frag mapping.

// LDS layout (bytes); weight row stride 1040 (520 bf16: 2-way bank alias = free)
#define WSTRIDE   1040
#define LDS_WA1   0        // W_ih1 slice  32 x 1040
#define LDS_WA0   33280    // W_hh0 slice
#define LDS_WB1   66560    // W_hh1 slice
#define LDS_WBU   99840    // U slice
#define LDS_W0C   133120   // chunk0 weights 32 x 64B
#define LDS_YROW  135168   // f32[256]
#define LDS_HST   136192   // u16[256][8]
#define LDS_TOTAL 140288

__device__ __forceinline__ float bf2f(short s) {
  u32 u = ((u32)(u16)s) << 16; float f; __builtin_memcpy(&f, &u, 4); return f;
}
__device__ __forceinline__ short f2bf(float f) {
  u32 u; __builtin_memcpy(&u, &f, 4);
  u = (u + 0x7fffu + ((u >> 16) & 1u)) >> 16; return (short)u;
}
__device__ __forceinline__ float sigm(float x) { return 1.f / (1.f + __expf(-x)); }
__device__ __forceinline__ float tanh_(float x) {
  float ax = fminf(fabsf(x), 15.f);
  float e = __expf(2.f * ax);
  float r = (e - 1.f) / (e + 1.f);
  return x < 0.f ? -r : r;
}

__device__ __forceinline__ u64 ald(const u64* p) {
  return __hip_atomic_load(p, __ATOMIC_RELAXED, __HIP_MEMORY_SCOPE_AGENT);
}
__device__ __forceinline__ void ast(u64* p, u64 v) {
  __hip_atomic_store(p, v, __ATOMIC_RELAXED, __HIP_MEMORY_SCOPE_AGENT);
}
__device__ __forceinline__ u32 ald32(const u32* p) {
  return __hip_atomic_load(p, __ATOMIC_RELAXED, __HIP_MEMORY_SCOPE_AGENT);
}
__device__ __forceinline__ void ast32(u32* p, u32 v) {
  __hip_atomic_store(p, v, __ATOMIC_RELAXED, __HIP_MEMORY_SCOPE_AGENT);
}

// device-scope 16B load (sc1: L2-bypass, L3-coherent); async until WAITV
#define LOADX4(dst, ptr, IMM) \
  asm volatile("global_load_dwordx4 %0, %1, off offset:" #IMM " sc1" : "=v"(dst) : "v"(ptr))
#define WAITV(N) do { \
  asm volatile("s_waitcnt vmcnt(" #N ")" ::: "memory"); \
  __builtin_amdgcn_sched_barrier(0); } while (0)

// one k-group = 4 tiles (4 k-chunks x 1KB), two row-blocks; lane-contiguous
#define IS8(r0,r1,r2,r3,r4,r5,r6,r7,p0,p1) do { \
  LOADX4(r0, p0, 0);    LOADX4(r1, p1, 0); \
  LOADX4(r2, p0, 1024); LOADX4(r3, p1, 1024); \
  LOADX4(r4, p0, 2048); LOADX4(r5, p1, 2048); \
  LOADX4(r6, p0, 3072); LOADX4(r7, p1, 3072); } while (0)

union vv { v4 u; s8 s; };
__device__ __forceinline__ s8 as_s8(v4 x) { vv t; t.u = x; return t.s; }
union uab { u64 q[2]; s8 v; };
union vf4 { v4 u; float f[4]; };
union f2u { float f[2]; u64 q; };

// ---------------- prep kernels ----------------
__global__ void prep_pack(const float* __restrict__ Wih0, const float* __restrict__ Whh0,
                          const float* __restrict__ Wih1, const float* __restrict__ Whh1,
                          const float* __restrict__ Wproj,
                          u16* __restrict__ W0C, u16* __restrict__ WIH1p,
                          u16* __restrict__ WHH0p, u16* __restrict__ WHH1p,
                          u16* __restrict__ Up) {
  int stride = gridDim.x * blockDim.x;
  int i0 = blockIdx.x * blockDim.x + threadIdx.x;
  for (int idx = i0; idx < G4 * 32; idx += stride) {
    int n = idx >> 5, k = idx & 31;
    W0C[idx] = (k < 9) ? (u16)f2bf(Wih0[n * 9 + k]) : (u16)0;
  }
  for (int idx = i0; idx < G4 * 512; idx += stride) {
    int n = idx >> 9, k = idx & 511;
    WIH1p[idx] = (u16)f2bf(Wih1[idx]);
    WHH0p[idx] = (u16)f2bf(Whh0[idx]);
    WHH1p[idx] = (u16)f2bf(Whh1[idx]);
    Up[idx]    = (u16)f2bf(Wih0[n * 9] * Wproj[k]);
  }
}

__global__ void prep_xe(const float* __restrict__ xf, const float* __restrict__ z,
                        const float* __restrict__ Wz, const float* __restrict__ bz,
                        const float* __restrict__ bproj, u16* __restrict__ xe) {
  int idx = blockIdx.x * blockDim.x + threadIdx.x;
  if (idx >= NSTEPS * B_SZ) return;
  int t = idx >> 10, b = idx & 1023;
  float zb[9];
#pragma unroll
  for (int i = 0; i < 9; i++) {
    float s = bz[i];
#pragma unroll
    for (int d = 0; d < 16; d++) s += z[b * 16 + d] * Wz[i * 16 + d];
    zb[i] = s;
  }
  __align__(16) u16 o[16];
  // t>0: prev_y = bpj + Wproj.h1 ; bpj const folded here, Wproj.h1 via U-gemm
  o[0] = (u16)f2bf(zb[0] + (t > 0 ? bproj[0] : 0.f));
#pragma unroll
  for (int e = 0; e < 8; e++) o[1 + e] = (u16)f2bf(xf[b * 512 + t * 8 + e] + zb[1 + e]);
#pragma unroll
  for (int k = 9; k < 16; k++) o[k] = 0;
  uint4* dst = (uint4*)(xe + (size_t)idx * 16);
  dst[0] = *(const uint4*)&o[0];
  dst[1] = *(const uint4*)&o[8];
}

// initial h -> TILED layout, slot 1
__global__ void prep_state(const float* __restrict__ h0in, u16* __restrict__ h0s,
                           u16* __restrict__ h1s, u32* __restrict__ flags) {
  int i = blockIdx.x * blockDim.x + threadIdx.x;
  if (i < B_SZ * H_SZ) {
    int r = i >> 9, k = i & 511;
    int ti = ((r >> 4) * 16 + (k >> 5)) * 512
           + ((r & 15) + (((k >> 3) & 3) << 4)) * 8 + (k & 7);
    h0s[524288 + ti] = (u16)f2bf(h0in[i]);
    h1s[524288 + ti] = (u16)f2bf(h0in[524288 + i]);
  }
  if (i < 256) flags[i] = 0;
}

// ---------------- main persistent kernel ----------------
struct MainParams {
  const float* y0; const float* c0;
  const float* bih0; const float* bhh0; const float* bih1; const float* bhh1;
  const float* wproj; const float* bproj;
  const u16* xe; const u16* w0c; const u16* wih1; const u16* whh0;
  const u16* whh1; const u16* up;
  u64* h0u; u64* h1u; float* ypart; u32* flags; float* out;
};

__device__ __forceinline__ f4 MFMA_(s8 a, s8 b, f4 c) {
  return __builtin_amdgcn_mfma_f32_16x16x32_bf16(a, b, c, 0, 0, 0);
}

// prologue-only: K=512 gemm, TILED h, intrinsic atomic loads (slow, runs once)
__device__ __forceinline__ void gemmK512_2(const u64* hb, int tb0, int tb1,
    const char* b0p, const char* b1p, f4 acc[4]) {
#pragma unroll
  for (int kc = 0; kc < 16; kc++) {
    uab a0; a0.q[0] = ald(hb + tb0 + kc * 128); a0.q[1] = ald(hb + tb0 + kc * 128 + 1);
    uab a1; a1.q[0] = ald(hb + tb1 + kc * 128); a1.q[1] = ald(hb + tb1 + kc * 128 + 1);
    s8 b0 = *(const s8*)(b0p + kc * 64);
    s8 b1 = *(const s8*)(b1p + kc * 64);
    acc[0] = MFMA_(a0.v, b0, acc[0]);
    acc[1] = MFMA_(a0.v, b1, acc[1]);
    acc[2] = MFMA_(a1.v, b0, acc[2]);
    acc[3] = MFMA_(a1.v, b1, acc[3]);
  }
}

// consume 8 regs (4 k-chunks x 2 row-blocks) feeding two acc sets
__device__ __forceinline__ void cons_dual8(
    v4 A0, v4 A1, v4 A2, v4 A3, v4 A4, v4 A5, v4 A6, v4 A7,
    const char* wq0, const char* wq1, const char* wp0, const char* wp1,
    f4 accQ[4], f4 accP[4]) {
#define DPAIR(x, y, OFF) do { \
    s8 bq0 = *(const s8*)(wq0 + OFF); s8 bq1 = *(const s8*)(wq1 + OFF); \
    s8 bp0 = *(const s8*)(wp0 + OFF); s8 bp1 = *(const s8*)(wp1 + OFF); \
    accQ[0] = MFMA_(x, bq0, accQ[0]); accQ[1] = MFMA_(x, bq1, accQ[1]); \
    accQ[2] = MFMA_(y, bq0, accQ[2]); accQ[3] = MFMA_(y, bq1, accQ[3]); \
    accP[0] = MFMA_(x, bp0, accP[0]); accP[1] = MFMA_(x, bp1, accP[1]); \
    accP[2] = MFMA_(y, bp0, accP[2]); accP[3] = MFMA_(y, bp1, accP[3]); } while (0)
  DPAIR(as_s8(A0), as_s8(A1), 0);
  DPAIR(as_s8(A2), as_s8(A3), 64);
  DPAIR(as_s8(A4), as_s8(A5), 128);
  DPAIR(as_s8(A6), as_s8(A7), 192);
#undef DPAIR
}

// arrival: per-wave vmcnt drain -> one relaxed flag store -> 1-wave poll of 64 slots
__device__ __forceinline__ void barrier_wait(u32* slots, int js, int tid, u32 target) {
  asm volatile("s_waitcnt vmcnt(0)" ::: "memory");
  __syncthreads();
  if (tid == 0) ast32(&slots[js], target);
  if (tid < 64) {
    int spins = 0;
    while (ald32(&slots[tid]) < target) {
      __builtin_amdgcn_s_sleep(1);
      if (++spins > (1 << 18)) break;   // fail-safe: never hang
    }
  }
  __syncthreads();
}

struct LaneCtx { int mb0, grp, pp, jl, hlf; };

// bias, lane^8 gate exchange (i,g <-> f,o), cell math, write h (bf16) to LDS stage
__device__ __forceinline__ void cell_update(f4 acc[4], const float bias[2], float cr[2][2],
    u16* __restrict__ hst, int lbase, const LaneCtx& L, float hval[2][2]) {
#pragma unroll
  for (int m = 0; m < 2; m++)
#pragma unroll
    for (int n = 0; n < 2; n++)
#pragma unroll
      for (int r = 0; r < 4; r++) acc[m * 2 + n][r] += bias[n];
  f4 rx[4];
#pragma unroll
  for (int q = 0; q < 4; q++)
#pragma unroll
    for (int r = 0; r < 4; r++) rx[q][r] = __shfl_xor(acc[q][r], 8);
#pragma unroll
  for (int mtl = 0; mtl < 2; mtl++) {
#pragma unroll
    for (int q = 0; q < 2; q++) {
      int r = L.hlf * 2 + q;
      float iv = L.hlf ? rx[mtl * 2 + 0][r] : acc[mtl * 2 + 0][r];
      float fv = L.hlf ? acc[mtl * 2 + 0][r] : rx[mtl * 2 + 0][r];
      float gv = L.hlf ? rx[mtl * 2 + 1][r] : acc[mtl * 2 + 1][r];
      float ov = L.hlf ? acc[mtl * 2 + 1][r] : rx[mtl * 2 + 1][r];
      float c2 = sigm(fv) * cr[mtl][q] + sigm(iv) * tanh_(gv);
      float hv = sigm(ov) * tanh_(c2);
      cr[mtl][q] = c2;
      hval[mtl][q] = hv;
      int lrow = lbase + mtl * 16 + L.grp * 4 + r;
      hst[lrow * 8 + L.jl] = (u16)f2bf(hv);
    }
  }
}

__global__ __launch_bounds__(512, 2) void lstm_main(MainParams p) {
  extern __shared__ char lds[];
  float* yrow = (float*)(lds + LDS_YROW);
  u16* hst = (u16*)(lds + LDS_HST);

  const int bx = blockIdx.x, chunk = bx >> 6, js = bx & 63;
  const int tid = threadIdx.x, lane = tid & 63, wid = tid >> 6;

  { // stage weight slices into LDS once
    int n = tid & 31, part = tid >> 5;
    int ng = ((n >> 3) << 9) + js * 8 + (n & 7);
#define STAGE(MATP, LOFF) do { \
    const u32* s_ = (const u32*)(p.MATP + (size_t)ng * 512); \
    u32* d_ = (u32*)(lds + LOFF + n * WSTRIDE + part * 64); \
    _Pragma("unroll") for (int q = 0; q < 16; q++) d_[q] = s_[part * 16 + q]; } while (0)
    STAGE(wih1, LDS_WA1);
    STAGE(whh0, LDS_WA0);
    STAGE(whh1, LDS_WB1);
    STAGE(up,   LDS_WBU);
#undef STAGE
    const u32* s0 = (const u32*)(p.w0c + (size_t)ng * 32);
    u32* d0 = (u32*)(lds + LDS_W0C + n * 64);
    d0[part] = s0[part];
    if (tid < 256) yrow[tid] = p.y0[chunk * 256 + tid];
  }

  LaneCtx L;
  L.grp = lane >> 4; L.pp = lane & 15; L.jl = lane & 7; L.hlf = (lane >> 3) & 1;
  L.mb0 = chunk * 256 + wid * 32;
  const int lbase = wid * 32;
  const int j = js * 8 + L.jl;
  const int rb0 = chunk * 16 + wid * 2;              // row-block of arow0 set
  const int aoff0 = rb0 * 16384 + lane * 16;         // TILED byte offset
  const int aoff1 = aoff0 + 16384;                   // next row-block
  const int tb0 = rb0 * 2048 + lane * 2;             // u64 idx (prologue)
  const int tb1 = tb0 + 2048;
  // producer store slot (tid<256): row r = chunk*256+tid
  const int pst = (chunk * 16 + (tid >> 4)) * 2048 + (js >> 2) * 128
                + ((tid & 15) + ((js & 3) << 4)) * 2;

  float bias0[2], bias1[2];
#pragma unroll
  for (int ntl = 0; ntl < 2; ntl++) {
    int n = ntl * 16 + L.pp;
    int ng = ((n >> 3) << 9) + js * 8 + (n & 7);
    bias0[ntl] = p.bih0[ng] + p.bhh0[ng];
    bias1[ntl] = p.bih1[ng] + p.bhh1[ng];
  }
  float wpj = p.wproj[j];
  float bpj = p.bproj[0];

  float c0r[2][2], c1r[2][2];
#pragma unroll
  for (int mtl = 0; mtl < 2; mtl++)
#pragma unroll
    for (int q = 0; q < 2; q++) {
      int row = L.mb0 + mtl * 16 + L.grp * 4 + L.hlf * 2 + q;
      c0r[mtl][q] = p.c0[row * 512 + j];
      c1r[mtl][q] = p.c0[524288 + row * 512 + j];
    }

  u32* flagc = p.flags + chunk * 64;
  const char* wA1_0 = lds + LDS_WA1 + L.pp * WSTRIDE + L.grp * 16;
  const char* wA1_1 = lds + LDS_WA1 + (16 + L.pp) * WSTRIDE + L.grp * 16;
  const char* wA0_0 = lds + LDS_WA0 + L.pp * WSTRIDE + L.grp * 16;
  const char* wA0_1 = lds + LDS_WA0 + (16 + L.pp) * WSTRIDE + L.grp * 16;
  const char* wB1_0 = lds + LDS_WB1 + L.pp * WSTRIDE + L.grp * 16;
  const char* wB1_1 = lds + LDS_WB1 + (16 + L.pp) * WSTRIDE + L.grp * 16;
  const char* wBU_0 = lds + LDS_WBU + L.pp * WSTRIDE + L.grp * 16;
  const char* wBU_1 = lds + LDS_WBU + (16 + L.pp) * WSTRIDE + L.grp * 16;
  const char* w0c_0 = lds + LDS_W0C + L.pp * 64 + L.grp * 16;
  const char* w0c_1 = lds + LDS_W0C + (16 + L.pp) * 64 + L.grp * 16;

  const int rot = js & 3;
  const int g0 = ((rot + 0) & 3) * 4096, g1 = ((rot + 1) & 3) * 4096;
  const int g2 = ((rot + 2) & 3) * 4096, g3 = ((rot + 3) & 3) * 4096;
  const int o0 = g0 >> 4, o1 = g1 >> 4, o2 = g2 >> 4, o3 = g3 >> 4;

  __syncthreads();

  f4 accP[4] = {{0,0,0,0},{0,0,0,0},{0,0,0,0},{0,0,0,0}};   // gates0 accum
  f4 accQ[4] = {{0,0,0,0},{0,0,0,0},{0,0,0,0},{0,0,0,0}};   // gates1 accum

  // ===== prologue: gates0(0) = Whh0 h0(-1) + chunk0(y0) ; carry Whh1 h1(-1) =====
  gemmK512_2(p.h0u + 131072, tb0, tb1, wA0_0, wA0_1, accP);
  {
    s8 a0 = {0,0,0,0,0,0,0,0}, a1 = {0,0,0,0,0,0,0,0};
    if (L.grp < 2) {
      const char* xb = (const char*)p.xe;   // t = 0
      a0 = *(const s8*)(xb + (L.mb0 + L.pp) * 32 + L.grp * 16);
      a1 = *(const s8*)(xb + (L.mb0 + 16 + L.pp) * 32 + L.grp * 16);
      if (L.grp == 0) {
        a0[0] = f2bf(bf2f(a0[0]) + yrow[wid * 32 + L.pp]);
        a1[0] = f2bf(bf2f(a1[0]) + yrow[wid * 32 + 16 + L.pp]);
      }
    }
    s8 b0 = *(const s8*)(w0c_0);
    s8 b1 = *(const s8*)(w0c_1);
    accP[0] = MFMA_(a0, b0, accP[0]);
    accP[1] = MFMA_(a0, b1, accP[1]);
    accP[2] = MFMA_(a1, b0, accP[2]);
    accP[3] = MFMA_(a1, b1, accP[3]);
  }
  {
    float hd[2][2];
    cell_update(accP, bias0, c0r, hst, lbase, L, hd);
  }
  gemmK512_2(p.h1u + 131072, tb0, tb1, wB1_0, wB1_1, accQ);  // Whh1 h1(-1) carry
  __syncthreads();
  if (tid < 256) {
    const u64* src = (const u64*)&hst[tid * 8];
    u64* dst = p.h0u + pst;   // slot 0 = h0(0)
    ast(dst, src[0]);
    ast(dst + 1, src[1]);
  }
  barrier_wait(flagc, js, tid, 1u);
#pragma unroll
  for (int q = 0; q < 4; q++) accP[q] = (f4){0, 0, 0, 0};

  v4 A0, A1, A2, A3, A4, A5, A6, A7;
  v4 C0, C1, C2, C3, C4, C5, C6, C7;

  for (int t = 0; t < NSTEPS; t++) {
    // ===== phase A: read h0(t); gates1(t) += Wih1 h0 ; gates0(t+1) += Whh0 h0 =====
    {
      const char* hb = (const char*)p.h0u + (size_t)(t & 1) * 1048576;
      const char* pa0 = hb + aoff0;
      const char* pa1 = hb + aoff1;
      IS8(A0,A1,A2,A3,A4,A5,A6,A7, pa0 + g0, pa1 + g0);
      IS8(C0,C1,C2,C3,C4,C5,C6,C7, pa0 + g1, pa1 + g1);
      WAITV(8);
      cons_dual8(A0,A1,A2,A3,A4,A5,A6,A7, wA1_0+o0, wA1_1+o0, wA0_0+o0, wA0_1+o0, accQ, accP);
      IS8(A0,A1,A2,A3,A4,A5,A6,A7, pa0 + g2, pa1 + g2);
      WAITV(8);
      cons_dual8(C0,C1,C2,C3,C4,C5,C6,C7, wA1_0+o1, wA1_1+o1, wA0_0+o1, wA0_1+o1, accQ, accP);
      IS8(C0,C1,C2,C3,C4,C5,C6,C7, pa0 + g3, pa1 + g3);
      WAITV(8);
      cons_dual8(A0,A1,A2,A3,A4,A5,A6,A7, wA1_0+o2, wA1_1+o2, wA0_0+o2, wA0_1+o2, accQ, accP);
      WAITV(0);
      cons_dual8(C0,C1,C2,C3,C4,C5,C6,C7, wA1_0+o3, wA1_1+o3, wA0_0+o3, wA0_1+o3, accQ, accP);

      float hval[2][2];
      cell_update(accQ, bias1, c1r, hst, lbase, L, hval);
      // proj partials -> ypart[js][row]: paired 8B stores tiling exact 64B lines
      {
        float py[2][2];
#pragma unroll
        for (int mtl = 0; mtl < 2; mtl++)
#pragma unroll
          for (int q = 0; q < 2; q++) {
            float s = hval[mtl][q] * wpj;
            s += __shfl_xor(s, 1);
            s += __shfl_xor(s, 2);
            s += __shfl_xor(s, 4);
            py[mtl][q] = s;
          }
        if (L.jl == 0) {
#pragma unroll
          for (int mtl = 0; mtl < 2; mtl++) {
            int row = L.mb0 + mtl * 16 + L.grp * 4 + L.hlf * 2;
            f2u u; u.f[0] = py[mtl][0]; u.f[1] = py[mtl][1];
            ast((u64*)((char*)p.ypart + (size_t)js * 4096 + (size_t)row * 4), u.q);
          }
        }
      }
      __syncthreads();
      if (tid < 256) {
        const u64* src = (const u64*)&hst[tid * 8];
        u64* dst = p.h1u + (size_t)(t & 1) * 131072 + pst;
        ast(dst, src[0]);
        ast(dst + 1, src[1]);
      }
      barrier_wait(flagc, js, tid, (u32)(2 * t + 2));
#pragma unroll
      for (int q = 0; q < 4; q++) accQ[q] = (f4){0, 0, 0, 0};
    }

    // ===== phase B: read h1(t); gates1(t+1) += Whh1 h1 ; gates0(t+1) += U h1 =====
    {
      const char* hb = (const char*)p.h1u + (size_t)(t & 1) * 1048576;
      const char* pb0 = hb + aoff0;
      const char* pb1 = hb + aoff1;
      IS8(A0,A1,A2,A3,A4,A5,A6,A7, pb0 + g0, pb1 + g0);
      IS8(C0,C1,C2,C3,C4,C5,C6,C7, pb0 + g1, pb1 + g1);
      // wave-0 only (R8-proven pattern): lane l reads js=l's 16B partial slice for
      // this block's 4 output rows; WAITV(0) over-drains wave 0 only; 64-lane
      // shfl-sum; lane 0 writes this block's 4 rows of out. No LDS, no js gating.
      if (tid < 64) {
        v4 Yv;
        const char* yq = (const char*)p.ypart + (size_t)lane * 4096
                       + (size_t)(chunk * 256 + js * 4) * 4;
        LOADX4(Yv, yq, 0);
        WAITV(0);
        vf4 w; w.u = Yv;
        float s0 = w.f[0], s1 = w.f[1], s2 = w.f[2], s3 = w.f[3];
#pragma unroll
        for (int m = 1; m < 64; m <<= 1) {
          s0 += __shfl_xor(s0, m);
          s1 += __shfl_xor(s1, m);
          s2 += __shfl_xor(s2, m);
          s3 += __shfl_xor(s3, m);
        }
        if (lane == 0) {
          int rb = chunk * 256 + js * 4;
          p.out[(rb + 0) * 64 + t] = s0 + bpj;
          p.out[(rb + 1) * 64 + t] = s1 + bpj;
          p.out[(rb + 2) * 64 + t] = s2 + bpj;
          p.out[(rb + 3) * 64 + t] = s3 + bpj;
        }
      }
      WAITV(8);
      cons_dual8(A0,A1,A2,A3,A4,A5,A6,A7, wB1_0+o0, wB1_1+o0, wBU_0+o0, wBU_1+o0, accQ, accP);
      IS8(A0,A1,A2,A3,A4,A5,A6,A7, pb0 + g2, pb1 + g2);
      WAITV(8);
      cons_dual8(C0,C1,C2,C3,C4,C5,C6,C7, wB1_0+o1, wB1_1+o1, wBU_0+o1, wBU_1+o1, accQ, accP);
      IS8(C0,C1,C2,C3,C4,C5,C6,C7, pb0 + g3, pb1 + g3);
      WAITV(8);
      cons_dual8(A0,A1,A2,A3,A4,A5,A6,A7, wB1_0+o2, wB1_1+o2, wBU_0+o2, wBU_1+o2, accQ, accP);
      WAITV(0);
      cons_dual8(C0,C1,C2,C3,C4,C5,C6,C7, wB1_0+o3, wB1_1+o3, wBU_0+o3, wBU_1+o3, accQ, accP);

      // chunk0 of gates0(t+1): exo+z(+bproj) const part (y folded into U + xe slot0)
      {
        int tn = (t < 63) ? t + 1 : 63;
        s8 a0 = {0,0,0,0,0,0,0,0}, a1 = {0,0,0,0,0,0,0,0};
        if (L.grp < 2) {
          const char* xb = (const char*)p.xe + (size_t)tn * 32768;
          a0 = *(const s8*)(xb + (L.mb0 + L.pp) * 32 + L.grp * 16);
          a1 = *(const s8*)(xb + (L.mb0 + 16 + L.pp) * 32 + L.grp * 16);
        }
        s8 b0 = *(const s8*)(w0c_0);
        s8 b1 = *(const s8*)(w0c_1);
        accP[0] = MFMA_(a0, b0, accP[0]);
        accP[1] = MFMA_(a0, b1, accP[1]);
        accP[2] = MFMA_(a1, b0, accP[2]);
        accP[3] = MFMA_(a1, b1, accP[3]);
      }
      float hd[2][2];
      cell_update(accP, bias0, c0r, hst, lbase, L, hd);
      __syncthreads();
      if (tid < 256) {
        const u64* src = (const u64*)&hst[tid * 8];
        u64* dst = p.h0u + (size_t)((t + 1) & 1) * 131072 + pst;
        ast(dst, src[0]);
        ast(dst + 1, src[1]);
      }
      barrier_wait(flagc, js, tid, (u32)(2 * t + 3));
#pragma unroll
      for (int q = 0; q < 4; q++) accP[q] = (f4){0, 0, 0, 0};
    }
  }
}

extern "C" void kernel_launch(void* const* d_in, const int* in_sizes, int n_in,
                              void* d_out, int out_size, void* d_ws, size_t ws_size,
                              hipStream_t stream) {
  const float* y0   = (const float*)d_in[0];
  const float* xf   = (const float*)d_in[1];
  const float* h0   = (const float*)d_in[2];
  const float* c0   = (const float*)d_in[3];
  const float* z    = (const float*)d_in[4];
  const float* Wih0 = (const float*)d_in[5];
  const float* Whh0 = (const float*)d_in[6];
  const float* bih0 = (const float*)d_in[7];
  const float* bhh0 = (const float*)d_in[8];
  const float* Wih1 = (const float*)d_in[9];
  const float* Whh1 = (const float*)d_in[10];
  const float* bih1 = (const float*)d_in[11];
  const float* bhh1 = (const float*)d_in[12];
  const float* Wpr  = (const float*)d_in[13];
  const float* bpr  = (const float*)d_in[14];
  const float* Wz   = (const float*)d_in[15];
  const float* bz   = (const float*)d_in[16];

  if (ws_size < WS_NEEDED) return;
  char* ws = (char*)d_ws;
  u16* xe    = (u16*)(ws + WS_XE);
  u16* w0c   = (u16*)(ws + WS_W0C);
  u16* wih1  = (u16*)(ws + WS_WIH1);
  u16* whh0  = (u16*)(ws + WS_WHH0);
  u16* whh1  = (u16*)(ws + WS_WHH1);
  u16* up    = (u16*)(ws + WS_UP);
  u64* h0u   = (u64*)(ws + WS_H0S);
  u64* h1u   = (u64*)(ws + WS_H1S);
  float* ypart = (float*)(ws + WS_YPART);
  u32* flags = (u32*)(ws + WS_FLAGS);

  prep_pack<<<1024, 256, 0, stream>>>(Wih0, Whh0, Wih1, Whh1, Wpr,
                                      w0c, wih1, whh0, whh1, up);
  prep_xe<<<256, 256, 0, stream>>>(xf, z, Wz, bz, bpr, xe);
  prep_state<<<2048, 256, 0, stream>>>(h0, (u16*)h0u, (u16*)h1u, flags);

  MainParams prm;
  prm.y0 = y0; prm.c0 = c0;
  prm.bih0 = bih0; prm.bhh0 = bhh0; prm.bih1 = bih1; prm.bhh1 = bhh1;
  prm.wproj = Wpr; prm.bproj = bpr;
  prm.xe = xe; prm.w0c = w0c; prm.wih1 = wih1; prm.whh0 = whh0;
  prm.whh1 = whh1; prm.up = up;
  prm.h0u = h0u; prm.h1u = h1u; prm.ypart = ypart; prm.flags = flags;
  prm.out = (float*)d_out;

  hipFuncSetAttribute((const void*)lstm_main, hipFuncAttributeMaxDynamicSharedMemorySize, LDS_TOTAL);
  void* args[] = { &prm };
  hipLaunchCooperativeKernel((void*)lstm_main, dim3(256), dim3(512), args, LDS_TOTAL, stream);
}

// Round 12
// 1437.750 us; speedup vs baseline: 1.1339x; 1.0411x over previous
//
#include <hip/hip_runtime.h>

typedef unsigned int u32;
typedef unsigned short u16;
typedef unsigned long long u64;
typedef short s8 __attribute__((ext_vector_type(8)));   // 8 x bf16 (as i16)
typedef float f4 __attribute__((ext_vector_type(4)));
typedef u32 v4 __attribute__((ext_vector_type(4)));     // 16B asm load payload

#define B_SZ   1024
#define H_SZ   512
#define G4     2048
#define NSTEPS 64

// ws layout (bytes)
#define WS_XE     0u          // [64][1024][16] bf16  = 2097152
#define WS_W0C    2097152u    // [2048][32]  bf16     = 131072
#define WS_WIH1   2228224u    // [2048][512] bf16     = 2097152
#define WS_WHH0   4325376u    // [2048][512] bf16     = 2097152
#define WS_WHH1   6422528u    // [2048][512] bf16     = 2097152
#define WS_UP     8519680u    // [2048][512] bf16     = 2097152  (U = wih0[:,0] x wproj)
#define WS_H0I    10616832u   // TILED initial h0 = 1048576
#define WS_H1I    11665408u   // TILED initial h1 = 1048576
#define WS_YPART  12713984u   // [64 js][1024 rows] f32 = 262144 (single-buffered)
#define WS_FLAGS  12976128u   // [4][64] u32 = 1024
#define WS_RINGS  12977152u   // h0 ring [P][1MB] then h1 ring [P][1MB]
// WS_NEEDED(P) = WS_RINGS + P*2097152 ; P=1 -> 15.07 MB (<= previously-granted)

// h TILED layout: tile(rblk=r>>4, kblk=k>>5) = 1KB at rblk*16384 + kblk*1024;
// inner byte = lane*16, lane = (r&15) + ((k>>3)&3)*16  == MFMA A-frag mapping.

// LDS layout (bytes); weight row stride 1040 (520 bf16: 2-way bank alias = free)
#define WSTRIDE   1040
#define LDS_WA1   0        // W_ih1 slice  32 x 1040
#define LDS_WA0   33280    // W_hh0 slice
#define LDS_WB1   66560    // W_hh1 slice
#define LDS_WBU   99840    // U slice
#define LDS_W0C   133120   // chunk0 weights 32 x 64B
#define LDS_YROW  135168   // f32[256]
#define LDS_HST   136192   // u16[256][8]
#define LDS_TOTAL 140288

__device__ __forceinline__ float bf2f(short s) {
  u32 u = ((u32)(u16)s) << 16; float f; __builtin_memcpy(&f, &u, 4); return f;
}
__device__ __forceinline__ short f2bf(float f) {
  u32 u; __builtin_memcpy(&u, &f, 4);
  u = (u + 0x7fffu + ((u >> 16) & 1u)) >> 16; return (short)u;
}
__device__ __forceinline__ float sigm(float x) { return 1.f / (1.f + __expf(-x)); }
__device__ __forceinline__ float tanh_(float x) {
  float ax = fminf(fabsf(x), 15.f);
  float e = __expf(2.f * ax);
  float r = (e - 1.f) / (e + 1.f);
  return x < 0.f ? -r : r;
}

__device__ __forceinline__ u64 ald(const u64* p) {
  return __hip_atomic_load(p, __ATOMIC_RELAXED, __HIP_MEMORY_SCOPE_AGENT);
}
__device__ __forceinline__ void ast(u64* p, u64 v) {
  __hip_atomic_store(p, v, __ATOMIC_RELAXED, __HIP_MEMORY_SCOPE_AGENT);
}
__device__ __forceinline__ u32 ald32(const u32* p) {
  return __hip_atomic_load(p, __ATOMIC_RELAXED, __HIP_MEMORY_SCOPE_AGENT);
}
__device__ __forceinline__ void ast32(u32* p, u32 v) {
  __hip_atomic_store(p, v, __ATOMIC_RELAXED, __HIP_MEMORY_SCOPE_AGENT);
}

// sc1 (coherent, L2-bypass) load: for ypart (rewritten every phase)
#define LOADX4(dst, ptr, IMM) \
  asm volatile("global_load_dwordx4 %0, %1, off offset:" #IMM " sc1" : "=v"(dst) : "v"(ptr))
// CACHEABLE load: for h rings (write-once slots; freshness via periodic acquire fence)
#define LOADX4C(dst, ptr, IMM) \
  asm volatile("global_load_dwordx4 %0, %1, off offset:" #IMM : "=v"(dst) : "v"(ptr))
#define WAITV(N) do { \
  asm volatile("s_waitcnt vmcnt(" #N ")" ::: "memory"); \
  __builtin_amdgcn_sched_barrier(0); } while (0)

// one k-group = 4 tiles (4 k-chunks x 1KB), two row-blocks; lane-contiguous
#define IS8(r0,r1,r2,r3,r4,r5,r6,r7,p0,p1) do { \
  LOADX4C(r0, p0, 0);    LOADX4C(r1, p1, 0); \
  LOADX4C(r2, p0, 1024); LOADX4C(r3, p1, 1024); \
  LOADX4C(r4, p0, 2048); LOADX4C(r5, p1, 2048); \
  LOADX4C(r6, p0, 3072); LOADX4C(r7, p1, 3072); } while (0)

union vv { v4 u; s8 s; };
__device__ __forceinline__ s8 as_s8(v4 x) { vv t; t.u = x; return t.s; }
union uab { u64 q[2]; s8 v; };
union vf4 { v4 u; float f[4]; };
union f2u { float f[2]; u64 q; };

// ---------------- prep kernels ----------------
__global__ void prep_pack(const float* __restrict__ Wih0, const float* __restrict__ Whh0,
                          const float* __restrict__ Wih1, const float* __restrict__ Whh1,
                          const float* __restrict__ Wproj,
                          u16* __restrict__ W0C, u16* __restrict__ WIH1p,
                          u16* __restrict__ WHH0p, u16* __restrict__ WHH1p,
                          u16* __restrict__ Up) {
  int stride = gridDim.x * blockDim.x;
  int i0 = blockIdx.x * blockDim.x + threadIdx.x;
  for (int idx = i0; idx < G4 * 32; idx += stride) {
    int n = idx >> 5, k = idx & 31;
    W0C[idx] = (k < 9) ? (u16)f2bf(Wih0[n * 9 + k]) : (u16)0;
  }
  for (int idx = i0; idx < G4 * 512; idx += stride) {
    int n = idx >> 9, k = idx & 511;
    WIH1p[idx] = (u16)f2bf(Wih1[idx]);
    WHH0p[idx] = (u16)f2bf(Whh0[idx]);
    WHH1p[idx] = (u16)f2bf(Whh1[idx]);
    Up[idx]    = (u16)f2bf(Wih0[n * 9] * Wproj[k]);
  }
}

__global__ void prep_xe(const float* __restrict__ xf, const float* __restrict__ z,
                        const float* __restrict__ Wz, const float* __restrict__ bz,
                        const float* __restrict__ bproj, u16* __restrict__ xe) {
  int idx = blockIdx.x * blockDim.x + threadIdx.x;
  if (idx >= NSTEPS * B_SZ) return;
  int t = idx >> 10, b = idx & 1023;
  float zb[9];
#pragma unroll
  for (int i = 0; i < 9; i++) {
    float s = bz[i];
#pragma unroll
    for (int d = 0; d < 16; d++) s += z[b * 16 + d] * Wz[i * 16 + d];
    zb[i] = s;
  }
  __align__(16) u16 o[16];
  o[0] = (u16)f2bf(zb[0] + (t > 0 ? bproj[0] : 0.f));
#pragma unroll
  for (int e = 0; e < 8; e++) o[1 + e] = (u16)f2bf(xf[b * 512 + t * 8 + e] + zb[1 + e]);
#pragma unroll
  for (int k = 9; k < 16; k++) o[k] = 0;
  uint4* dst = (uint4*)(xe + (size_t)idx * 16);
  dst[0] = *(const uint4*)&o[0];
  dst[1] = *(const uint4*)&o[8];
}

// initial h -> TILED dedicated buffers
__global__ void prep_state(const float* __restrict__ h0in, u16* __restrict__ h0i,
                           u16* __restrict__ h1i, u32* __restrict__ flags) {
  int i = blockIdx.x * blockDim.x + threadIdx.x;
  if (i < B_SZ * H_SZ) {
    int r = i >> 9, k = i & 511;
    int ti = ((r >> 4) * 16 + (k >> 5)) * 512
           + ((r & 15) + (((k >> 3) & 3) << 4)) * 8 + (k & 7);
    h0i[ti] = (u16)f2bf(h0in[i]);
    h1i[ti] = (u16)f2bf(h0in[524288 + i]);
  }
  if (i < 256) flags[i] = 0;
}

// ---------------- main persistent kernel ----------------
struct MainParams {
  const float* y0; const float* c0;
  const float* bih0; const float* bhh0; const float* bih1; const float* bhh1;
  const float* wproj; const float* bproj;
  const u16* xe; const u16* w0c; const u16* wih1; const u16* whh0;
  const u16* whh1; const u16* up;
  const u64* h0i; const u64* h1i;
  u64* h0r; u64* h1r;             // write-once rings, P slots x 1MB
  float* ypart; u32* flags; float* out;
  u32 smask;                       // P-1 (P power of 2)
};

__device__ __forceinline__ f4 MFMA_(s8 a, s8 b, f4 c) {
  return __builtin_amdgcn_mfma_f32_16x16x32_bf16(a, b, c, 0, 0, 0);
}

// prologue-only: K=512 gemm, TILED h, intrinsic atomic loads (slow, runs once)
__device__ __forceinline__ void gemmK512_2(const u64* hb, int tb0, int tb1,
    const char* b0p, const char* b1p, f4 acc[4]) {
#pragma unroll
  for (int kc = 0; kc < 16; kc++) {
    uab a0; a0.q[0] = ald(hb + tb0 + kc * 128); a0.q[1] = ald(hb + tb0 + kc * 128 + 1);
    uab a1; a1.q[0] = ald(hb + tb1 + kc * 128); a1.q[1] = ald(hb + tb1 + kc * 128 + 1);
    s8 b0 = *(const s8*)(b0p + kc * 64);
    s8 b1 = *(const s8*)(b1p + kc * 64);
    acc[0] = MFMA_(a0.v, b0, acc[0]);
    acc[1] = MFMA_(a0.v, b1, acc[1]);
    acc[2] = MFMA_(a1.v, b0, acc[2]);
    acc[3] = MFMA_(a1.v, b1, acc[3]);
  }
}

// consume 8 regs (4 k-chunks x 2 row-blocks) feeding two acc sets
__device__ __forceinline__ void cons_dual8(
    v4 A0, v4 A1, v4 A2, v4 A3, v4 A4, v4 A5, v4 A6, v4 A7,
    const char* wq0, const char* wq1, const char* wp0, const char* wp1,
    f4 accQ[4], f4 accP[4]) {
#define DPAIR(x, y, OFF) do { \
    s8 bq0 = *(const s8*)(wq0 + OFF); s8 bq1 = *(const s8*)(wq1 + OFF); \
    s8 bp0 = *(const s8*)(wp0 + OFF); s8 bp1 = *(const s8*)(wp1 + OFF); \
    accQ[0] = MFMA_(x, bq0, accQ[0]); accQ[1] = MFMA_(x, bq1, accQ[1]); \
    accQ[2] = MFMA_(y, bq0, accQ[2]); accQ[3] = MFMA_(y, bq1, accQ[3]); \
    accP[0] = MFMA_(x, bp0, accP[0]); accP[1] = MFMA_(x, bp1, accP[1]); \
    accP[2] = MFMA_(y, bp0, accP[2]); accP[3] = MFMA_(y, bp1, accP[3]); } while (0)
  DPAIR(as_s8(A0), as_s8(A1), 0);
  DPAIR(as_s8(A2), as_s8(A3), 64);
  DPAIR(as_s8(A4), as_s8(A5), 128);
  DPAIR(as_s8(A6), as_s8(A7), 192);
#undef DPAIR
}

// arrival: per-wave vmcnt drain -> one relaxed flag store -> 1-wave poll of 64 slots
__device__ __forceinline__ void barrier_wait(u32* slots, int js, int tid, u32 target) {
  asm volatile("s_waitcnt vmcnt(0)" ::: "memory");
  __syncthreads();
  if (tid == 0) ast32(&slots[js], target);
  if (tid < 64) {
    int spins = 0;
    while (ald32(&slots[tid]) < target) {
      __builtin_amdgcn_s_sleep(1);
      if (++spins > (1 << 18)) break;   // fail-safe: never hang
    }
  }
  __syncthreads();
}

struct LaneCtx { int mb0, grp, pp, jl, hlf; };

// bias, lane^8 gate exchange (i,g <-> f,o), cell math, write h (bf16) to LDS stage
__device__ __forceinline__ void cell_update(f4 acc[4], const float bias[2], float cr[2][2],
    u16* __restrict__ hst, int lbase, const LaneCtx& L, float hval[2][2]) {
#pragma unroll
  for (int m = 0; m < 2; m++)
#pragma unroll
    for (int n = 0; n < 2; n++)
#pragma unroll
      for (int r = 0; r < 4; r++) acc[m * 2 + n][r] += bias[n];
  f4 rx[4];
#pragma unroll
  for (int q = 0; q < 4; q++)
#pragma unroll
    for (int r = 0; r < 4; r++) rx[q][r] = __shfl_xor(acc[q][r], 8);
#pragma unroll
  for (int mtl = 0; mtl < 2; mtl++) {
#pragma unroll
    for (int q = 0; q < 2; q++) {
      int r = L.hlf * 2 + q;
      float iv = L.hlf ? rx[mtl * 2 + 0][r] : acc[mtl * 2 + 0][r];
      float fv = L.hlf ? acc[mtl * 2 + 0][r] : rx[mtl * 2 + 0][r];
      float gv = L.hlf ? rx[mtl * 2 + 1][r] : acc[mtl * 2 + 1][r];
      float ov = L.hlf ? acc[mtl * 2 + 1][r] : rx[mtl * 2 + 1][r];
      float c2 = sigm(fv) * cr[mtl][q] + sigm(iv) * tanh_(gv);
      float hv = sigm(ov) * tanh_(c2);
      cr[mtl][q] = c2;
      hval[mtl][q] = hv;
      int lrow = lbase + mtl * 16 + L.grp * 4 + r;
      hst[lrow * 8 + L.jl] = (u16)f2bf(hv);
    }
  }
}

__global__ __launch_bounds__(512, 2) void lstm_main(MainParams p) {
  extern __shared__ char lds[];
  float* yrow = (float*)(lds + LDS_YROW);
  u16* hst = (u16*)(lds + LDS_HST);

  const int bx = blockIdx.x, chunk = bx >> 6, js = bx & 63;
  const int tid = threadIdx.x, lane = tid & 63, wid = tid >> 6;

  { // stage weight slices into LDS once
    int n = tid & 31, part = tid >> 5;
    int ng = ((n >> 3) << 9) + js * 8 + (n & 7);
#define STAGE(MATP, LOFF) do { \
    const u32* s_ = (const u32*)(p.MATP + (size_t)ng * 512); \
    u32* d_ = (u32*)(lds + LOFF + n * WSTRIDE + part * 64); \
    _Pragma("unroll") for (int q = 0; q < 16; q++) d_[q] = s_[part * 16 + q]; } while (0)
    STAGE(wih1, LDS_WA1);
    STAGE(whh0, LDS_WA0);
    STAGE(whh1, LDS_WB1);
    STAGE(up,   LDS_WBU);
#undef STAGE
    const u32* s0 = (const u32*)(p.w0c + (size_t)ng * 32);
    u32* d0 = (u32*)(lds + LDS_W0C + n * 64);
    d0[part] = s0[part];
    if (tid < 256) yrow[tid] = p.y0[chunk * 256 + tid];
  }

  LaneCtx L;
  L.grp = lane >> 4; L.pp = lane & 15; L.jl = lane & 7; L.hlf = (lane >> 3) & 1;
  L.mb0 = chunk * 256 + wid * 32;
  const int lbase = wid * 32;
  const int j = js * 8 + L.jl;
  const int rb0 = chunk * 16 + wid * 2;              // row-block of arow0 set
  const int aoff0 = rb0 * 16384 + lane * 16;         // TILED byte offset
  const int aoff1 = aoff0 + 16384;                   // next row-block
  const int tb0 = rb0 * 2048 + lane * 2;             // u64 idx (prologue)
  const int tb1 = tb0 + 2048;
  // producer store slot (tid<256): row r = chunk*256+tid
  const int pst = (chunk * 16 + (tid >> 4)) * 2048 + (js >> 2) * 128
                + ((tid & 15) + ((js & 3) << 4)) * 2;
  const u32 smask = p.smask;

  float bias0[2], bias1[2];
#pragma unroll
  for (int ntl = 0; ntl < 2; ntl++) {
    int n = ntl * 16 + L.pp;
    int ng = ((n >> 3) << 9) + js * 8 + (n & 7);
    bias0[ntl] = p.bih0[ng] + p.bhh0[ng];
    bias1[ntl] = p.bih1[ng] + p.bhh1[ng];
  }
  float wpj = p.wproj[j];
  float bpj = p.bproj[0];

  float c0r[2][2], c1r[2][2];
#pragma unroll
  for (int mtl = 0; mtl < 2; mtl++)
#pragma unroll
    for (int q = 0; q < 2; q++) {
      int row = L.mb0 + mtl * 16 + L.grp * 4 + L.hlf * 2 + q;
      c0r[mtl][q] = p.c0[row * 512 + j];
      c1r[mtl][q] = p.c0[524288 + row * 512 + j];
    }

  u32* flagc = p.flags + chunk * 64;
  const char* wA1_0 = lds + LDS_WA1 + L.pp * WSTRIDE + L.grp * 16;
  const char* wA1_1 = lds + LDS_WA1 + (16 + L.pp) * WSTRIDE + L.grp * 16;
  const char* wA0_0 = lds + LDS_WA0 + L.pp * WSTRIDE + L.grp * 16;
  const char* wA0_1 = lds + LDS_WA0 + (16 + L.pp) * WSTRIDE + L.grp * 16;
  const char* wB1_0 = lds + LDS_WB1 + L.pp * WSTRIDE + L.grp * 16;
  const char* wB1_1 = lds + LDS_WB1 + (16 + L.pp) * WSTRIDE + L.grp * 16;
  const char* wBU_0 = lds + LDS_WBU + L.pp * WSTRIDE + L.grp * 16;
  const char* wBU_1 = lds + LDS_WBU + (16 + L.pp) * WSTRIDE + L.grp * 16;
  const char* w0c_0 = lds + LDS_W0C + L.pp * 64 + L.grp * 16;
  const char* w0c_1 = lds + LDS_W0C + (16 + L.pp) * 64 + L.grp * 16;

  const int rot = js & 3;
  const int g0 = ((rot + 0) & 3) * 4096, g1 = ((rot + 1) & 3) * 4096;
  const int g2 = ((rot + 2) & 3) * 4096, g3 = ((rot + 3) & 3) * 4096;
  const int o0 = g0 >> 4, o1 = g1 >> 4, o2 = g2 >> 4, o3 = g3 >> 4;

  __syncthreads();

  f4 accP[4] = {{0,0,0,0},{0,0,0,0},{0,0,0,0},{0,0,0,0}};   // gates0 accum
  f4 accQ[4] = {{0,0,0,0},{0,0,0,0},{0,0,0,0},{0,0,0,0}};   // gates1 accum

  // ===== prologue: gates0(0) = Whh0 h0(-1) + chunk0(y0) ; carry Whh1 h1(-1) =====
  gemmK512_2(p.h0i, tb0, tb1, wA0_0, wA0_1, accP);
  {
    s8 a0 = {0,0,0,0,0,0,0,0}, a1 = {0,0,0,0,0,0,0,0};
    if (L.grp < 2) {
      const char* xb = (const char*)p.xe;   // t = 0
      a0 = *(const s8*)(xb + (L.mb0 + L.pp) * 32 + L.grp * 16);
      a1 = *(const s8*)(xb + (L.mb0 + 16 + L.pp) * 32 + L.grp * 16);
      if (L.grp == 0) {
        a0[0] = f2bf(bf2f(a0[0]) + yrow[wid * 32 + L.pp]);
        a1[0] = f2bf(bf2f(a1[0]) + yrow[wid * 32 + 16 + L.pp]);
      }
    }
    s8 b0 = *(const s8*)(w0c_0);
    s8 b1 = *(const s8*)(w0c_1);
    accP[0] = MFMA_(a0, b0, accP[0]);
    accP[1] = MFMA_(a0, b1, accP[1]);
    accP[2] = MFMA_(a1, b0, accP[2]);
    accP[3] = MFMA_(a1, b1, accP[3]);
  }
  {
    float hd[2][2];
    cell_update(accP, bias0, c0r, hst, lbase, L, hd);
  }
  gemmK512_2(p.h1i, tb0, tb1, wB1_0, wB1_1, accQ);  // Whh1 h1(-1) carry
  __syncthreads();
  if (tid < 256) {
    const u64* src = (const u64*)&hst[tid * 8];
    u64* dst = p.h0r + pst;   // ring slot 0 = h0(0)
    ast(dst, src[0]);
    ast(dst + 1, src[1]);
  }
  barrier_wait(flagc, js, tid, 1u);
#pragma unroll
  for (int q = 0; q < 4; q++) accP[q] = (f4){0, 0, 0, 0};

  v4 A0, A1, A2, A3, A4, A5, A6, A7;
  v4 C0, C1, C2, C3, C4, C5, C6, C7;

  for (int t = 0; t < NSTEPS; t++) {
    // periodic aligned acquire fence: drop L1/L2 lines older than one ring period.
    // Fires at t=0 (also covers cross-graph-replay staleness) then every P steps.
    if (((u32)t & smask) == 0) __builtin_amdgcn_fence(__ATOMIC_ACQUIRE, "agent");

    // ===== phase A: read h0(t); gates1(t) += Wih1 h0 ; gates0(t+1) += Whh0 h0 =====
    {
      const char* hb = (const char*)p.h0r + (size_t)((u32)t & smask) * 1048576;
      const char* pa0 = hb + aoff0;
      const char* pa1 = hb + aoff1;
      IS8(A0,A1,A2,A3,A4,A5,A6,A7, pa0 + g0, pa1 + g0);
      IS8(C0,C1,C2,C3,C4,C5,C6,C7, pa0 + g1, pa1 + g1);
      WAITV(8);
      cons_dual8(A0,A1,A2,A3,A4,A5,A6,A7, wA1_0+o0, wA1_1+o0, wA0_0+o0, wA0_1+o0, accQ, accP);
      IS8(A0,A1,A2,A3,A4,A5,A6,A7, pa0 + g2, pa1 + g2);
      WAITV(8);
      cons_dual8(C0,C1,C2,C3,C4,C5,C6,C7, wA1_0+o1, wA1_1+o1, wA0_0+o1, wA0_1+o1, accQ, accP);
      IS8(C0,C1,C2,C3,C4,C5,C6,C7, pa0 + g3, pa1 + g3);
      WAITV(8);
      cons_dual8(A0,A1,A2,A3,A4,A5,A6,A7, wA1_0+o2, wA1_1+o2, wA0_0+o2, wA0_1+o2, accQ, accP);
      WAITV(0);
      cons_dual8(C0,C1,C2,C3,C4,C5,C6,C7, wA1_0+o3, wA1_1+o3, wA0_0+o3, wA0_1+o3, accQ, accP);

      float hval[2][2];
      cell_update(accQ, bias1, c1r, hst, lbase, L, hval);
      // proj partials -> ypart[js][row]: paired 8B stores tiling exact 64B lines
      {
        float py[2][2];
#pragma unroll
        for (int mtl = 0; mtl < 2; mtl++)
#pragma unroll
          for (int q = 0; q < 2; q++) {
            float s = hval[mtl][q] * wpj;
            s += __shfl_xor(s, 1);
            s += __shfl_xor(s, 2);
            s += __shfl_xor(s, 4);
            py[mtl][q] = s;
          }
        if (L.jl == 0) {
#pragma unroll
          for (int mtl = 0; mtl < 2; mtl++) {
            int row = L.mb0 + mtl * 16 + L.grp * 4 + L.hlf * 2;
            f2u u; u.f[0] = py[mtl][0]; u.f[1] = py[mtl][1];
            ast((u64*)((char*)p.ypart + (size_t)js * 4096 + (size_t)row * 4), u.q);
          }
        }
      }
      __syncthreads();
      if (tid < 256) {
        const u64* src = (const u64*)&hst[tid * 8];
        u64* dst = p.h1r + (size_t)((u32)t & smask) * 131072 + pst;
        ast(dst, src[0]);
        ast(dst + 1, src[1]);
      }
      barrier_wait(flagc, js, tid, (u32)(2 * t + 2));
#pragma unroll
      for (int q = 0; q < 4; q++) accQ[q] = (f4){0, 0, 0, 0};
    }

    // ===== phase B: read h1(t); gates1(t+1) += Whh1 h1 ; gates0(t+1) += U h1 =====
    {
      const char* hb = (const char*)p.h1r + (size_t)((u32)t & smask) * 1048576;
      const char* pb0 = hb + aoff0;
      const char* pb1 = hb + aoff1;
      IS8(A0,A1,A2,A3,A4,A5,A6,A7, pb0 + g0, pb1 + g0);
      IS8(C0,C1,C2,C3,C4,C5,C6,C7, pb0 + g1, pb1 + g1);
      // wave-0 only: lane l reads js=l's 16B partial slice for this block's 4
      // output rows (sc1); WAITV(0) over-drains wave 0 only; 64-lane shfl-sum.
      if (tid < 64) {
        v4 Yv;
        const char* yq = (const char*)p.ypart + (size_t)lane * 4096
                       + (size_t)(chunk * 256 + js * 4) * 4;
        LOADX4(Yv, yq, 0);
        WAITV(0);
        vf4 w; w.u = Yv;
        float s0 = w.f[0], s1 = w.f[1], s2 = w.f[2], s3 = w.f[3];
#pragma unroll
        for (int m = 1; m < 64; m <<= 1) {
          s0 += __shfl_xor(s0, m);
          s1 += __shfl_xor(s1, m);
          s2 += __shfl_xor(s2, m);
          s3 += __shfl_xor(s3, m);
        }
        if (lane == 0) {
          int rb = chunk * 256 + js * 4;
          p.out[(rb + 0) * 64 + t] = s0 + bpj;
          p.out[(rb + 1) * 64 + t] = s1 + bpj;
          p.out[(rb + 2) * 64 + t] = s2 + bpj;
          p.out[(rb + 3) * 64 + t] = s3 + bpj;
        }
      }
      WAITV(8);
      cons_dual8(A0,A1,A2,A3,A4,A5,A6,A7, wB1_0+o0, wB1_1+o0, wBU_0+o0, wBU_1+o0, accQ, accP);
      IS8(A0,A1,A2,A3,A4,A5,A6,A7, pb0 + g2, pb1 + g2);
      WAITV(8);
      cons_dual8(C0,C1,C2,C3,C4,C5,C6,C7, wB1_0+o1, wB1_1+o1, wBU_0+o1, wBU_1+o1, accQ, accP);
      IS8(C0,C1,C2,C3,C4,C5,C6,C7, pb0 + g3, pb1 + g3);
      WAITV(8);
      cons_dual8(A0,A1,A2,A3,A4,A5,A6,A7, wB1_0+o2, wB1_1+o2, wBU_0+o2, wBU_1+o2, accQ, accP);
      WAITV(0);
      cons_dual8(C0,C1,C2,C3,C4,C5,C6,C7, wB1_0+o3, wB1_1+o3, wBU_0+o3, wBU_1+o3, accQ, accP);

      // chunk0 of gates0(t+1): exo+z(+bproj) const part (y folded into U + xe slot0)
      {
        int tn = (t < 63) ? t + 1 : 63;
        s8 a0 = {0,0,0,0,0,0,0,0}, a1 = {0,0,0,0,0,0,0,0};
        if (L.grp < 2) {
          const char* xb = (const char*)p.xe + (size_t)tn * 32768;
          a0 = *(const s8*)(xb + (L.mb0 + L.pp) * 32 + L.grp * 16);
          a1 = *(const s8*)(xb + (L.mb0 + 16 + L.pp) * 32 + L.grp * 16);
        }
        s8 b0 = *(const s8*)(w0c_0);
        s8 b1 = *(const s8*)(w0c_1);
        accP[0] = MFMA_(a0, b0, accP[0]);
        accP[1] = MFMA_(a0, b1, accP[1]);
        accP[2] = MFMA_(a1, b0, accP[2]);
        accP[3] = MFMA_(a1, b1, accP[3]);
      }
      float hd[2][2];
      cell_update(accP, bias0, c0r, hst, lbase, L, hd);
      __syncthreads();
      if (tid < 256) {
        const u64* src = (const u64*)&hst[tid * 8];
        u64* dst = p.h0r + (size_t)((u32)(t + 1) & smask) * 131072 + pst;
        ast(dst, src[0]);
        ast(dst + 1, src[1]);
      }
      barrier_wait(flagc, js, tid, (u32)(2 * t + 3));
#pragma unroll
      for (int q = 0; q < 4; q++) accP[q] = (f4){0, 0, 0, 0};
    }
  }
}

extern "C" void kernel_launch(void* const* d_in, const int* in_sizes, int n_in,
                              void* d_out, int out_size, void* d_ws, size_t ws_size,
                              hipStream_t stream) {
  const float* y0   = (const float*)d_in[0];
  const float* xf   = (const float*)d_in[1];
  const float* h0   = (const float*)d_in[2];
  const float* c0   = (const float*)d_in[3];
  const float* z    = (const float*)d_in[4];
  const float* Wih0 = (const float*)d_in[5];
  const float* Whh0 = (const float*)d_in[6];
  const float* bih0 = (const float*)d_in[7];
  const float* bhh0 = (const float*)d_in[8];
  const float* Wih1 = (const float*)d_in[9];
  const float* Whh1 = (const float*)d_in[10];
  const float* bih1 = (const float*)d_in[11];
  const float* bhh1 = (const float*)d_in[12];
  const float* Wpr  = (const float*)d_in[13];
  const float* bpr  = (const float*)d_in[14];
  const float* Wz   = (const float*)d_in[15];
  const float* bz   = (const float*)d_in[16];

  // ring sizing: largest power-of-2 P <= 16 that fits; P=1 needs ~15.1 MB
  u32 P = 16;
  while (P > 1 && (size_t)WS_RINGS + (size_t)P * 2097152ull > ws_size) P >>= 1;
  if ((size_t)WS_RINGS + (size_t)P * 2097152ull > ws_size) return;

  char* ws = (char*)d_ws;
  u16* xe    = (u16*)(ws + WS_XE);
  u16* w0c   = (u16*)(ws + WS_W0C);
  u16* wih1  = (u16*)(ws + WS_WIH1);
  u16* whh0  = (u16*)(ws + WS_WHH0);
  u16* whh1  = (u16*)(ws + WS_WHH1);
  u16* up    = (u16*)(ws + WS_UP);
  u64* h0i   = (u64*)(ws + WS_H0I);
  u64* h1i   = (u64*)(ws + WS_H1I);
  float* ypart = (float*)(ws + WS_YPART);
  u32* flags = (u32*)(ws + WS_FLAGS);
  u64* h0r   = (u64*)(ws + WS_RINGS);
  u64* h1r   = (u64*)(ws + WS_RINGS + (size_t)P * 1048576ull);

  prep_pack<<<1024, 256, 0, stream>>>(Wih0, Whh0, Wih1, Whh1, Wpr,
                                      w0c, wih1, whh0, whh1, up);
  prep_xe<<<256, 256, 0, stream>>>(xf, z, Wz, bz, bpr, xe);
  prep_state<<<2048, 256, 0, stream>>>(h0, (u16*)h0i, (u16*)h1i, flags);

  MainParams prm;
  prm.y0 = y0; prm.c0 = c0;
  prm.bih0 = bih0; prm.bhh0 = bhh0; prm.bih1 = bih1; prm.bhh1 = bhh1;
  prm.wproj = Wpr; prm.bproj = bpr;
  prm.xe = xe; prm.w0c = w0c; prm.wih1 = wih1; prm.whh0 = whh0;
  prm.whh1 = whh1; prm.up = up;
  prm.h0i = h0i; prm.h1i = h1i;
  prm.h0r = h0r; prm.h1r = h1r;
  prm.ypart = ypart; prm.flags = flags;
  prm.out = (float*)d_out;
  prm.smask = P - 1;

  hipFuncSetAttribute((const void*)lstm_main, hipFuncAttributeMaxDynamicSharedMemorySize, LDS_TOTAL);
  void* args[] = { &prm };
  hipLaunchCooperativeKernel((void*)lstm_main, dim3(256), dim3(512), args, LDS_TOTAL, stream);
}

// Round 13
// 1201.695 us; speedup vs baseline: 1.3566x; 1.1964x over previous
//
#include <hip/hip_runtime.h>

typedef unsigned int u32;
typedef unsigned short u16;
typedef unsigned long long u64;
typedef short s8 __attribute__((ext_vector_type(8)));   // 8 x bf16 (as i16)
typedef float f4 __attribute__((ext_vector_type(4)));
typedef u32 v4 __attribute__((ext_vector_type(4)));     // 16B asm load payload

#define B_SZ   1024
#define H_SZ   512
#define G4     2048
#define NSTEPS 64

// ws layout (bytes)
#define WS_XE     0u          // [64][1024][16] bf16  = 2097152
#define WS_W0C    2097152u    // [2048][32]  bf16     = 131072
#define WS_WIH1   2228224u    // [2048][512] bf16     = 2097152
#define WS_WHH0   4325376u    // [2048][512] bf16     = 2097152
#define WS_WHH1   6422528u    // [2048][512] bf16     = 2097152
#define WS_UP     8519680u    // [2048][512] bf16     = 2097152  (U = wih0[:,0] x wproj)
#define WS_H0S    10616832u   // [2][TILED 1024x512] bf16 = 2097152
#define WS_H1S    12713984u   // [2][TILED 1024x512] bf16 = 2097152
#define WS_YPART  14811136u   // [64 js][1024 rows] f32 = 262144
#define WS_FLAGS  15335424u   // [4][64] u32          = 1024
#define WS_NEEDED 15336448u

// h TILED layout: tile(rblk=r>>4, kblk=k>>5) = 1KB at rblk*16384 + kblk*1024;
// inner byte = lane*16, lane = (r&15) + ((k>>3)&3)*16  == MFMA A-frag mapping.
// Producer js writes ONLY kblk = js>>2  =>  k-quarter q = js>>4 has exactly
// 16 producers js in [16q, 16q+16). Consumers gate per-quarter (qwait).

// LDS layout (bytes); weight row stride 1040 (520 bf16: 2-way bank alias = free)
#define WSTRIDE   1040
#define LDS_WA1   0        // W_ih1 slice  32 x 1040
#define LDS_WA0   33280    // W_hh0 slice
#define LDS_WB1   66560    // W_hh1 slice
#define LDS_WBU   99840    // U slice
#define LDS_W0C   133120   // chunk0 weights 32 x 64B
#define LDS_YROW  135168   // f32[256]
#define LDS_HST   136192   // u16[256][8]
#define LDS_TOTAL 140288

__device__ __forceinline__ float bf2f(short s) {
  u32 u = ((u32)(u16)s) << 16; float f; __builtin_memcpy(&f, &u, 4); return f;
}
__device__ __forceinline__ short f2bf(float f) {
  u32 u; __builtin_memcpy(&u, &f, 4);
  u = (u + 0x7fffu + ((u >> 16) & 1u)) >> 16; return (short)u;
}
__device__ __forceinline__ float sigm(float x) { return 1.f / (1.f + __expf(-x)); }
__device__ __forceinline__ float tanh_(float x) {
  float ax = fminf(fabsf(x), 15.f);
  float e = __expf(2.f * ax);
  float r = (e - 1.f) / (e + 1.f);
  return x < 0.f ? -r : r;
}

__device__ __forceinline__ u64 ald(const u64* p) {
  return __hip_atomic_load(p, __ATOMIC_RELAXED, __HIP_MEMORY_SCOPE_AGENT);
}
__device__ __forceinline__ void ast(u64* p, u64 v) {
  __hip_atomic_store(p, v, __ATOMIC_RELAXED, __HIP_MEMORY_SCOPE_AGENT);
}
__device__ __forceinline__ u32 ald32(const u32* p) {
  return __hip_atomic_load(p, __ATOMIC_RELAXED, __HIP_MEMORY_SCOPE_AGENT);
}
__device__ __forceinline__ void ast32(u32* p, u32 v) {
  __hip_atomic_store(p, v, __ATOMIC_RELAXED, __HIP_MEMORY_SCOPE_AGENT);
}

// device-scope 16B load (sc1: L2-bypass, L3-coherent); async until WAITV
#define LOADX4(dst, ptr, IMM) \
  asm volatile("global_load_dwordx4 %0, %1, off offset:" #IMM " sc1" : "=v"(dst) : "v"(ptr))
#define WAITV(N) do { \
  asm volatile("s_waitcnt vmcnt(" #N ")" ::: "memory"); \
  __builtin_amdgcn_sched_barrier(0); } while (0)

// one k-group = 4 tiles (4 k-chunks x 1KB), two row-blocks; lane-contiguous
#define IS8(r0,r1,r2,r3,r4,r5,r6,r7,p0,p1) do { \
  LOADX4(r0, p0, 0);    LOADX4(r1, p1, 0); \
  LOADX4(r2, p0, 1024); LOADX4(r3, p1, 1024); \
  LOADX4(r4, p0, 2048); LOADX4(r5, p1, 2048); \
  LOADX4(r6, p0, 3072); LOADX4(r7, p1, 3072); } while (0)

union vv { v4 u; s8 s; };
__device__ __forceinline__ s8 as_s8(v4 x) { vv t; t.u = x; return t.s; }
union uab { u64 q[2]; s8 v; };
union vf4 { v4 u; float f[4]; };
union f2u { float f[2]; u64 q; };

// ---------------- prep kernels ----------------
__global__ void prep_pack(const float* __restrict__ Wih0, const float* __restrict__ Whh0,
                          const float* __restrict__ Wih1, const float* __restrict__ Whh1,
                          const float* __restrict__ Wproj,
                          u16* __restrict__ W0C, u16* __restrict__ WIH1p,
                          u16* __restrict__ WHH0p, u16* __restrict__ WHH1p,
                          u16* __restrict__ Up) {
  int stride = gridDim.x * blockDim.x;
  int i0 = blockIdx.x * blockDim.x + threadIdx.x;
  for (int idx = i0; idx < G4 * 32; idx += stride) {
    int n = idx >> 5, k = idx & 31;
    W0C[idx] = (k < 9) ? (u16)f2bf(Wih0[n * 9 + k]) : (u16)0;
  }
  for (int idx = i0; idx < G4 * 512; idx += stride) {
    int n = idx >> 9, k = idx & 511;
    WIH1p[idx] = (u16)f2bf(Wih1[idx]);
    WHH0p[idx] = (u16)f2bf(Whh0[idx]);
    WHH1p[idx] = (u16)f2bf(Whh1[idx]);
    Up[idx]    = (u16)f2bf(Wih0[n * 9] * Wproj[k]);
  }
}

__global__ void prep_xe(const float* __restrict__ xf, const float* __restrict__ z,
                        const float* __restrict__ Wz, const float* __restrict__ bz,
                        const float* __restrict__ bproj, u16* __restrict__ xe) {
  int idx = blockIdx.x * blockDim.x + threadIdx.x;
  if (idx >= NSTEPS * B_SZ) return;
  int t = idx >> 10, b = idx & 1023;
  float zb[9];
#pragma unroll
  for (int i = 0; i < 9; i++) {
    float s = bz[i];
#pragma unroll
    for (int d = 0; d < 16; d++) s += z[b * 16 + d] * Wz[i * 16 + d];
    zb[i] = s;
  }
  __align__(16) u16 o[16];
  o[0] = (u16)f2bf(zb[0] + (t > 0 ? bproj[0] : 0.f));
#pragma unroll
  for (int e = 0; e < 8; e++) o[1 + e] = (u16)f2bf(xf[b * 512 + t * 8 + e] + zb[1 + e]);
#pragma unroll
  for (int k = 9; k < 16; k++) o[k] = 0;
  uint4* dst = (uint4*)(xe + (size_t)idx * 16);
  dst[0] = *(const uint4*)&o[0];
  dst[1] = *(const uint4*)&o[8];
}

// initial h -> TILED layout, slot 1
__global__ void prep_state(const float* __restrict__ h0in, u16* __restrict__ h0s,
                           u16* __restrict__ h1s, u32* __restrict__ flags) {
  int i = blockIdx.x * blockDim.x + threadIdx.x;
  if (i < B_SZ * H_SZ) {
    int r = i >> 9, k = i & 511;
    int ti = ((r >> 4) * 16 + (k >> 5)) * 512
           + ((r & 15) + (((k >> 3) & 3) << 4)) * 8 + (k & 7);
    h0s[524288 + ti] = (u16)f2bf(h0in[i]);
    h1s[524288 + ti] = (u16)f2bf(h0in[524288 + i]);
  }
  if (i < 256) flags[i] = 0;
}

// ---------------- main persistent kernel ----------------
struct MainParams {
  const float* y0; const float* c0;
  const float* bih0; const float* bhh0; const float* bih1; const float* bhh1;
  const float* wproj; const float* bproj;
  const u16* xe; const u16* w0c; const u16* wih1; const u16* whh0;
  const u16* whh1; const u16* up;
  u64* h0u; u64* h1u; float* ypart; u32* flags; float* out;
};

__device__ __forceinline__ f4 MFMA_(s8 a, s8 b, f4 c) {
  return __builtin_amdgcn_mfma_f32_16x16x32_bf16(a, b, c, 0, 0, 0);
}

// prologue-only: K=512 gemm, TILED h, intrinsic atomic loads (slow, runs once)
__device__ __forceinline__ void gemmK512_2(const u64* hb, int tb0, int tb1,
    const char* b0p, const char* b1p, f4 acc[4]) {
#pragma unroll
  for (int kc = 0; kc < 16; kc++) {
    uab a0; a0.q[0] = ald(hb + tb0 + kc * 128); a0.q[1] = ald(hb + tb0 + kc * 128 + 1);
    uab a1; a1.q[0] = ald(hb + tb1 + kc * 128); a1.q[1] = ald(hb + tb1 + kc * 128 + 1);
    s8 b0 = *(const s8*)(b0p + kc * 64);
    s8 b1 = *(const s8*)(b1p + kc * 64);
    acc[0] = MFMA_(a0.v, b0, acc[0]);
    acc[1] = MFMA_(a0.v, b1, acc[1]);
    acc[2] = MFMA_(a1.v, b0, acc[2]);
    acc[3] = MFMA_(a1.v, b1, acc[3]);
  }
}

// consume 8 regs (4 k-chunks x 2 row-blocks) feeding two acc sets
__device__ __forceinline__ void cons_dual8(
    v4 A0, v4 A1, v4 A2, v4 A3, v4 A4, v4 A5, v4 A6, v4 A7,
    const char* wq0, const char* wq1, const char* wp0, const char* wp1,
    f4 accQ[4], f4 accP[4]) {
#define DPAIR(x, y, OFF) do { \
    s8 bq0 = *(const s8*)(wq0 + OFF); s8 bq1 = *(const s8*)(wq1 + OFF); \
    s8 bp0 = *(const s8*)(wp0 + OFF); s8 bp1 = *(const s8*)(wp1 + OFF); \
    accQ[0] = MFMA_(x, bq0, accQ[0]); accQ[1] = MFMA_(x, bq1, accQ[1]); \
    accQ[2] = MFMA_(y, bq0, accQ[2]); accQ[3] = MFMA_(y, bq1, accQ[3]); \
    accP[0] = MFMA_(x, bp0, accP[0]); accP[1] = MFMA_(x, bp1, accP[1]); \
    accP[2] = MFMA_(y, bp0, accP[2]); accP[3] = MFMA_(y, bp1, accP[3]); } while (0)
  DPAIR(as_s8(A0), as_s8(A1), 0);
  DPAIR(as_s8(A2), as_s8(A3), 64);
  DPAIR(as_s8(A4), as_s8(A5), 128);
  DPAIR(as_s8(A6), as_s8(A7), 192);
#undef DPAIR
}

// per-wave quarter wait: lanes 0..15 poll the 16 producer flags of quarter q.
// A "memory" fence + sched_barrier pins subsequent volatile-asm loads after it.
__device__ __forceinline__ void qwait(const u32* flagc, int q, u32 target, int lane) {
  int spins = 0;
  for (;;) {
    u32 v = (lane < 16) ? ald32(&flagc[q * 16 + lane]) : target;
    if (__all(v >= target)) break;
    __builtin_amdgcn_s_sleep(1);
    if (++spins > (1 << 18)) break;   // fail-safe: never hang
  }
  __builtin_amdgcn_sched_barrier(0);
  asm volatile("" ::: "memory");
}

// arrival: own stores drained -> block-wide join -> bump own flag to phase#
__device__ __forceinline__ void arrive(u32* flagc, int js, int tid, u32 val) {
  asm volatile("s_waitcnt vmcnt(0)" ::: "memory");
  __syncthreads();
  if (tid == 0) ast32(&flagc[js], val);
}

struct LaneCtx { int mb0, grp, pp, jl, hlf; };

// bias, lane^8 gate exchange (i,g <-> f,o), cell math, write h (bf16) to LDS stage
__device__ __forceinline__ void cell_update(f4 acc[4], const float bias[2], float cr[2][2],
    u16* __restrict__ hst, int lbase, const LaneCtx& L, float hval[2][2]) {
#pragma unroll
  for (int m = 0; m < 2; m++)
#pragma unroll
    for (int n = 0; n < 2; n++)
#pragma unroll
      for (int r = 0; r < 4; r++) acc[m * 2 + n][r] += bias[n];
  f4 rx[4];
#pragma unroll
  for (int q = 0; q < 4; q++)
#pragma unroll
    for (int r = 0; r < 4; r++) rx[q][r] = __shfl_xor(acc[q][r], 8);
#pragma unroll
  for (int mtl = 0; mtl < 2; mtl++) {
#pragma unroll
    for (int q = 0; q < 2; q++) {
      int r = L.hlf * 2 + q;
      float iv = L.hlf ? rx[mtl * 2 + 0][r] : acc[mtl * 2 + 0][r];
      float fv = L.hlf ? acc[mtl * 2 + 0][r] : rx[mtl * 2 + 0][r];
      float gv = L.hlf ? rx[mtl * 2 + 1][r] : acc[mtl * 2 + 1][r];
      float ov = L.hlf ? acc[mtl * 2 + 1][r] : rx[mtl * 2 + 1][r];
      float c2 = sigm(fv) * cr[mtl][q] + sigm(iv) * tanh_(gv);
      float hv = sigm(ov) * tanh_(c2);
      cr[mtl][q] = c2;
      hval[mtl][q] = hv;
      int lrow = lbase + mtl * 16 + L.grp * 4 + r;
      hst[lrow * 8 + L.jl] = (u16)f2bf(hv);
    }
  }
}

__global__ __launch_bounds__(512, 2) void lstm_main(MainParams p) {
  extern __shared__ char lds[];
  float* yrow = (float*)(lds + LDS_YROW);
  u16* hst = (u16*)(lds + LDS_HST);

  const int bx = blockIdx.x, chunk = bx >> 6, js = bx & 63;
  const int tid = threadIdx.x, lane = tid & 63, wid = tid >> 6;

  { // stage weight slices into LDS once
    int n = tid & 31, part = tid >> 5;
    int ng = ((n >> 3) << 9) + js * 8 + (n & 7);
#define STAGE(MATP, LOFF) do { \
    const u32* s_ = (const u32*)(p.MATP + (size_t)ng * 512); \
    u32* d_ = (u32*)(lds + LOFF + n * WSTRIDE + part * 64); \
    _Pragma("unroll") for (int q = 0; q < 16; q++) d_[q] = s_[part * 16 + q]; } while (0)
    STAGE(wih1, LDS_WA1);
    STAGE(whh0, LDS_WA0);
    STAGE(whh1, LDS_WB1);
    STAGE(up,   LDS_WBU);
#undef STAGE
    const u32* s0 = (const u32*)(p.w0c + (size_t)ng * 32);
    u32* d0 = (u32*)(lds + LDS_W0C + n * 64);
    d0[part] = s0[part];
    if (tid < 256) yrow[tid] = p.y0[chunk * 256 + tid];
  }

  LaneCtx L;
  L.grp = lane >> 4; L.pp = lane & 15; L.jl = lane & 7; L.hlf = (lane >> 3) & 1;
  L.mb0 = chunk * 256 + wid * 32;
  const int lbase = wid * 32;
  const int j = js * 8 + L.jl;
  const int rb0 = chunk * 16 + wid * 2;              // row-block of arow0 set
  const int aoff0 = rb0 * 16384 + lane * 16;         // TILED byte offset
  const int aoff1 = aoff0 + 16384;                   // next row-block
  const int tb0 = rb0 * 2048 + lane * 2;             // u64 idx (prologue)
  const int tb1 = tb0 + 2048;
  // producer store slot (tid<256): row r = chunk*256+tid, kblk = js>>2
  const int pst = (chunk * 16 + (tid >> 4)) * 2048 + (js >> 2) * 128
                + ((tid & 15) + ((js & 3) << 4)) * 2;

  float bias0[2], bias1[2];
#pragma unroll
  for (int ntl = 0; ntl < 2; ntl++) {
    int n = ntl * 16 + L.pp;
    int ng = ((n >> 3) << 9) + js * 8 + (n & 7);
    bias0[ntl] = p.bih0[ng] + p.bhh0[ng];
    bias1[ntl] = p.bih1[ng] + p.bhh1[ng];
  }
  float wpj = p.wproj[j];
  float bpj = p.bproj[0];

  float c0r[2][2], c1r[2][2];
#pragma unroll
  for (int mtl = 0; mtl < 2; mtl++)
#pragma unroll
    for (int q = 0; q < 2; q++) {
      int row = L.mb0 + mtl * 16 + L.grp * 4 + L.hlf * 2 + q;
      c0r[mtl][q] = p.c0[row * 512 + j];
      c1r[mtl][q] = p.c0[524288 + row * 512 + j];
    }

  u32* flagc = p.flags + chunk * 64;
  const char* wA1_0 = lds + LDS_WA1 + L.pp * WSTRIDE + L.grp * 16;
  const char* wA1_1 = lds + LDS_WA1 + (16 + L.pp) * WSTRIDE + L.grp * 16;
  const char* wA0_0 = lds + LDS_WA0 + L.pp * WSTRIDE + L.grp * 16;
  const char* wA0_1 = lds + LDS_WA0 + (16 + L.pp) * WSTRIDE + L.grp * 16;
  const char* wB1_0 = lds + LDS_WB1 + L.pp * WSTRIDE + L.grp * 16;
  const char* wB1_1 = lds + LDS_WB1 + (16 + L.pp) * WSTRIDE + L.grp * 16;
  const char* wBU_0 = lds + LDS_WBU + L.pp * WSTRIDE + L.grp * 16;
  const char* wBU_1 = lds + LDS_WBU + (16 + L.pp) * WSTRIDE + L.grp * 16;
  const char* w0c_0 = lds + LDS_W0C + L.pp * 64 + L.grp * 16;
  const char* w0c_1 = lds + LDS_W0C + (16 + L.pp) * 64 + L.grp * 16;

  const int rot = js & 3;
  const int q0 = (rot + 0) & 3, q1 = (rot + 1) & 3;
  const int q2 = (rot + 2) & 3, q3 = (rot + 3) & 3;
  const int g0 = q0 * 4096, g1 = q1 * 4096, g2 = q2 * 4096, g3 = q3 * 4096;
  const int o0 = g0 >> 4, o1 = g1 >> 4, o2 = g2 >> 4, o3 = g3 >> 4;

  __syncthreads();

  f4 accP[4] = {{0,0,0,0},{0,0,0,0},{0,0,0,0},{0,0,0,0}};   // gates0 accum
  f4 accQ[4] = {{0,0,0,0},{0,0,0,0},{0,0,0,0},{0,0,0,0}};   // gates1 accum

  // ===== prologue: gates0(0) = Whh0 h0(-1) + chunk0(y0) ; carry Whh1 h1(-1) =====
  gemmK512_2(p.h0u + 131072, tb0, tb1, wA0_0, wA0_1, accP);
  {
    s8 a0 = {0,0,0,0,0,0,0,0}, a1 = {0,0,0,0,0,0,0,0};
    if (L.grp < 2) {
      const char* xb = (const char*)p.xe;   // t = 0
      a0 = *(const s8*)(xb + (L.mb0 + L.pp) * 32 + L.grp * 16);
      a1 = *(const s8*)(xb + (L.mb0 + 16 + L.pp) * 32 + L.grp * 16);
      if (L.grp == 0) {
        a0[0] = f2bf(bf2f(a0[0]) + yrow[wid * 32 + L.pp]);
        a1[0] = f2bf(bf2f(a1[0]) + yrow[wid * 32 + 16 + L.pp]);
      }
    }
    s8 b0 = *(const s8*)(w0c_0);
    s8 b1 = *(const s8*)(w0c_1);
    accP[0] = MFMA_(a0, b0, accP[0]);
    accP[1] = MFMA_(a0, b1, accP[1]);
    accP[2] = MFMA_(a1, b0, accP[2]);
    accP[3] = MFMA_(a1, b1, accP[3]);
  }
  {
    float hd[2][2];
    cell_update(accP, bias0, c0r, hst, lbase, L, hd);
  }
  gemmK512_2(p.h1u + 131072, tb0, tb1, wB1_0, wB1_1, accQ);  // Whh1 h1(-1) carry
  __syncthreads();
  if (tid < 256) {
    const u64* src = (const u64*)&hst[tid * 8];
    u64* dst = p.h0u + pst;   // slot 0 = h0(0)
    ast(dst, src[0]);
    ast(dst + 1, src[1]);
  }
  arrive(flagc, js, tid, 1u);
#pragma unroll
  for (int q = 0; q < 4; q++) accP[q] = (f4){0, 0, 0, 0};

  v4 A0, A1, A2, A3, A4, A5, A6, A7;
  v4 C0, C1, C2, C3, C4, C5, C6, C7;

  for (int t = 0; t < NSTEPS; t++) {
    // ===== phase A: read h0(t); gates1(t) += Wih1 h0 ; gates0(t+1) += Whh0 h0 =====
    {
      const u32 tg = (u32)(2 * t + 1);
      const char* hb = (const char*)p.h0u + (size_t)(t & 1) * 1048576;
      const char* pa0 = hb + aoff0;
      const char* pa1 = hb + aoff1;
      qwait(flagc, q0, tg, lane);
      IS8(A0,A1,A2,A3,A4,A5,A6,A7, pa0 + g0, pa1 + g0);
      qwait(flagc, q1, tg, lane);
      IS8(C0,C1,C2,C3,C4,C5,C6,C7, pa0 + g1, pa1 + g1);
      WAITV(8);
      cons_dual8(A0,A1,A2,A3,A4,A5,A6,A7, wA1_0+o0, wA1_1+o0, wA0_0+o0, wA0_1+o0, accQ, accP);
      qwait(flagc, q2, tg, lane);
      IS8(A0,A1,A2,A3,A4,A5,A6,A7, pa0 + g2, pa1 + g2);
      WAITV(8);
      cons_dual8(C0,C1,C2,C3,C4,C5,C6,C7, wA1_0+o1, wA1_1+o1, wA0_0+o1, wA0_1+o1, accQ, accP);
      qwait(flagc, q3, tg, lane);
      IS8(C0,C1,C2,C3,C4,C5,C6,C7, pa0 + g3, pa1 + g3);
      WAITV(8);
      cons_dual8(A0,A1,A2,A3,A4,A5,A6,A7, wA1_0+o2, wA1_1+o2, wA0_0+o2, wA0_1+o2, accQ, accP);
      WAITV(0);
      cons_dual8(C0,C1,C2,C3,C4,C5,C6,C7, wA1_0+o3, wA1_1+o3, wA0_0+o3, wA0_1+o3, accQ, accP);

      float hval[2][2];
      cell_update(accQ, bias1, c1r, hst, lbase, L, hval);
      // proj partials -> ypart[js][row]: paired 8B stores tiling exact 64B lines
      {
        float py[2][2];
#pragma unroll
        for (int mtl = 0; mtl < 2; mtl++)
#pragma unroll
          for (int q = 0; q < 2; q++) {
            float s = hval[mtl][q] * wpj;
            s += __shfl_xor(s, 1);
            s += __shfl_xor(s, 2);
            s += __shfl_xor(s, 4);
            py[mtl][q] = s;
          }
        if (L.jl == 0) {
#pragma unroll
          for (int mtl = 0; mtl < 2; mtl++) {
            int row = L.mb0 + mtl * 16 + L.grp * 4 + L.hlf * 2;
            f2u u; u.f[0] = py[mtl][0]; u.f[1] = py[mtl][1];
            ast((u64*)((char*)p.ypart + (size_t)js * 4096 + (size_t)row * 4), u.q);
          }
        }
      }
      __syncthreads();
      if (tid < 256) {
        const u64* src = (const u64*)&hst[tid * 8];
        u64* dst = p.h1u + (size_t)(t & 1) * 131072 + pst;
        ast(dst, src[0]);
        ast(dst + 1, src[1]);
      }
      arrive(flagc, js, tid, tg + 1);
#pragma unroll
      for (int q = 0; q < 4; q++) accQ[q] = (f4){0, 0, 0, 0};
    }

    // ===== phase B: read h1(t); gates1(t+1) += Whh1 h1 ; gates0(t+1) += U h1 =====
    {
      const u32 tg = (u32)(2 * t + 2);
      const char* hb = (const char*)p.h1u + (size_t)(t & 1) * 1048576;
      const char* pb0 = hb + aoff0;
      const char* pb1 = hb + aoff1;
      qwait(flagc, q0, tg, lane);
      IS8(A0,A1,A2,A3,A4,A5,A6,A7, pb0 + g0, pb1 + g0);
      qwait(flagc, q1, tg, lane);
      IS8(C0,C1,C2,C3,C4,C5,C6,C7, pb0 + g1, pb1 + g1);
      WAITV(8);
      cons_dual8(A0,A1,A2,A3,A4,A5,A6,A7, wB1_0+o0, wB1_1+o0, wBU_0+o0, wBU_1+o0, accQ, accP);
      qwait(flagc, q2, tg, lane);
      IS8(A0,A1,A2,A3,A4,A5,A6,A7, pb0 + g2, pb1 + g2);
      WAITV(8);
      cons_dual8(C0,C1,C2,C3,C4,C5,C6,C7, wB1_0+o1, wB1_1+o1, wBU_0+o1, wBU_1+o1, accQ, accP);
      qwait(flagc, q3, tg, lane);   // after this, ALL 64 producers of A(t) arrived
      IS8(C0,C1,C2,C3,C4,C5,C6,C7, pb0 + g3, pb1 + g3);
      // wave-0: y-reduce of step t (gated: all ypart producers arrived above).
      // WAITV(0) over-drains wave 0 only.
      if (tid < 64) {
        v4 Yv;
        const char* yq = (const char*)p.ypart + (size_t)lane * 4096
                       + (size_t)(chunk * 256 + js * 4) * 4;
        LOADX4(Yv, yq, 0);
        WAITV(0);
        vf4 w; w.u = Yv;
        float s0 = w.f[0], s1 = w.f[1], s2 = w.f[2], s3 = w.f[3];
#pragma unroll
        for (int m = 1; m < 64; m <<= 1) {
          s0 += __shfl_xor(s0, m);
          s1 += __shfl_xor(s1, m);
          s2 += __shfl_xor(s2, m);
          s3 += __shfl_xor(s3, m);
        }
        if (lane == 0) {
          int rb = chunk * 256 + js * 4;
          p.out[(rb + 0) * 64 + t] = s0 + bpj;
          p.out[(rb + 1) * 64 + t] = s1 + bpj;
          p.out[(rb + 2) * 64 + t] = s2 + bpj;
          p.out[(rb + 3) * 64 + t] = s3 + bpj;
        }
      }
      WAITV(8);
      cons_dual8(A0,A1,A2,A3,A4,A5,A6,A7, wB1_0+o2, wB1_1+o2, wBU_0+o2, wBU_1+o2, accQ, accP);
      WAITV(0);
      cons_dual8(C0,C1,C2,C3,C4,C5,C6,C7, wB1_0+o3, wB1_1+o3, wBU_0+o3, wBU_1+o3, accQ, accP);

      // chunk0 of gates0(t+1): exo+z(+bproj) const part (y folded into U + xe slot0)
      {
        int tn = (t < 63) ? t + 1 : 63;
        s8 a0 = {0,0,0,0,0,0,0,0}, a1 = {0,0,0,0,0,0,0,0};
        if (L.grp < 2) {
          const char* xb = (const char*)p.xe + (size_t)tn * 32768;
          a0 = *(const s8*)(xb + (L.mb0 + L.pp) * 32 + L.grp * 16);
          a1 = *(const s8*)(xb + (L.mb0 + 16 + L.pp) * 32 + L.grp * 16);
        }
        s8 b0 = *(const s8*)(w0c_0);
        s8 b1 = *(const s8*)(w0c_1);
        accP[0] = MFMA_(a0, b0, accP[0]);
        accP[1] = MFMA_(a0, b1, accP[1]);
        accP[2] = MFMA_(a1, b0, accP[2]);
        accP[3] = MFMA_(a1, b1, accP[3]);
      }
      float hd[2][2];
      cell_update(accP, bias0, c0r, hst, lbase, L, hd);
      __syncthreads();
      if (tid < 256) {
        const u64* src = (const u64*)&hst[tid * 8];
        u64* dst = p.h0u + (size_t)((t + 1) & 1) * 131072 + pst;
        ast(dst, src[0]);
        ast(dst + 1, src[1]);
      }
      arrive(flagc, js, tid, tg + 1);
#pragma unroll
      for (int q = 0; q < 4; q++) accP[q] = (f4){0, 0, 0, 0};
    }
  }
}

extern "C" void kernel_launch(void* const* d_in, const int* in_sizes, int n_in,
                              void* d_out, int out_size, void* d_ws, size_t ws_size,
                              hipStream_t stream) {
  const float* y0   = (const float*)d_in[0];
  const float* xf   = (const float*)d_in[1];
  const float* h0   = (const float*)d_in[2];
  const float* c0   = (const float*)d_in[3];
  const float* z    = (const float*)d_in[4];
  const float* Wih0 = (const float*)d_in[5];
  const float* Whh0 = (const float*)d_in[6];
  const float* bih0 = (const float*)d_in[7];
  const float* bhh0 = (const float*)d_in[8];
  const float* Wih1 = (const float*)d_in[9];
  const float* Whh1 = (const float*)d_in[10];
  const float* bih1 = (const float*)d_in[11];
  const float* bhh1 = (const float*)d_in[12];
  const float* Wpr  = (const float*)d_in[13];
  const float* bpr  = (const float*)d_in[14];
  const float* Wz   = (const float*)d_in[15];
  const float* bz   = (const float*)d_in[16];

  if (ws_size < WS_NEEDED) return;
  char* ws = (char*)d_ws;
  u16* xe    = (u16*)(ws + WS_XE);
  u16* w0c   = (u16*)(ws + WS_W0C);
  u16* wih1  = (u16*)(ws + WS_WIH1);
  u16* whh0  = (u16*)(ws + WS_WHH0);
  u16* whh1  = (u16*)(ws + WS_WHH1);
  u16* up    = (u16*)(ws + WS_UP);
  u64* h0u   = (u64*)(ws + WS_H0S);
  u64* h1u   = (u64*)(ws + WS_H1S);
  float* ypart = (float*)(ws + WS_YPART);
  u32* flags = (u32*)(ws + WS_FLAGS);

  prep_pack<<<1024, 256, 0, stream>>>(Wih0, Whh0, Wih1, Whh1, Wpr,
                                      w0c, wih1, whh0, whh1, up);
  prep_xe<<<256, 256, 0, stream>>>(xf, z, Wz, bz, bpr, xe);
  prep_state<<<2048, 256, 0, stream>>>(h0, (u16*)h0u, (u16*)h1u, flags);

  MainParams prm;
  prm.y0 = y0; prm.c0 = c0;
  prm.bih0 = bih0; prm.bhh0 = bhh0; prm.bih1 = bih1; prm.bhh1 = bhh1;
  prm.wproj = Wpr; prm.bproj = bpr;
  prm.xe = xe; prm.w0c = w0c; prm.wih1 = wih1; prm.whh0 = whh0;
  prm.whh1 = whh1; prm.up = up;
  prm.h0u = h0u; prm.h1u = h1u; prm.ypart = ypart; prm.flags = flags;
  prm.out = (float*)d_out;

  hipFuncSetAttribute((const void*)lstm_main, hipFuncAttributeMaxDynamicSharedMemorySize, LDS_TOTAL);
  void* args[] = { &prm };
  hipLaunchCooperativeKernel((void*)lstm_main, dim3(256), dim3(512), args, LDS_TOTAL, stream);
}

// Round 14
// 1153.799 us; speedup vs baseline: 1.4129x; 1.0415x over previous
//
#include <hip/hip_runtime.h>

typedef unsigned int u32;
typedef unsigned short u16;
typedef unsigned long long u64;
typedef short s8 __attribute__((ext_vector_type(8)));   // 8 x bf16 (as i16)
typedef float f4 __attribute__((ext_vector_type(4)));
typedef u32 v4 __attribute__((ext_vector_type(4)));     // 16B asm load payload

#define B_SZ   1024
#define H_SZ   512
#define G4     2048
#define NSTEPS 64

// ws layout (bytes)
#define WS_XE     0u          // [64][1024][16] bf16  = 2097152
#define WS_W0C    2097152u    // [2048][32]  bf16     = 131072
#define WS_WIH1   2228224u    // [2048][512] bf16     = 2097152
#define WS_WHH0   4325376u    // [2048][512] bf16     = 2097152
#define WS_WHH1   6422528u    // [2048][512] bf16     = 2097152
#define WS_UP     8519680u    // [2048][512] bf16     = 2097152  (U = wih0[:,0] x wproj)
#define WS_H0S    10616832u   // [2][TILED 1024x512] bf16 = 2097152
#define WS_H1S    12713984u   // [2][TILED 1024x512] bf16 = 2097152
#define WS_YPART  14811136u   // [64 js][1024 rows] f32 = 262144
#define WS_FLAGS  15335424u   // [4][64] u32          = 1024
#define WS_NEEDED 15336448u

// h TILED layout: tile(rblk=r>>4, kblk=k>>5) = 1KB at rblk*16384 + kblk*1024;
// inner byte = lane*16, lane = (r&15) + ((k>>3)&3)*16  == MFMA A-frag mapping.
// Producer js writes ONLY kblk = js>>2  =>  k-quarter q = js>>4 has exactly
// 16 producers js in [16q, 16q+16). Consumers gate per-quarter (qwait).

// LDS layout (bytes); weight row stride 1040 (520 bf16: 2-way bank alias = free)
#define WSTRIDE   1040
#define LDS_WA1   0        // W_ih1 slice  32 x 1040
#define LDS_WA0   33280    // W_hh0 slice
#define LDS_WB1   66560    // W_hh1 slice
#define LDS_WBU   99840    // U slice
#define LDS_W0C   133120   // chunk0 weights 32 x 64B
#define LDS_YROW  135168   // f32[256]
#define LDS_HST   136192   // u16[256][8]
#define LDS_TOTAL 140288

__device__ __forceinline__ float bf2f(short s) {
  u32 u = ((u32)(u16)s) << 16; float f; __builtin_memcpy(&f, &u, 4); return f;
}
__device__ __forceinline__ short f2bf(float f) {
  u32 u; __builtin_memcpy(&u, &f, 4);
  u = (u + 0x7fffu + ((u >> 16) & 1u)) >> 16; return (short)u;
}
__device__ __forceinline__ float sigm(float x) { return 1.f / (1.f + __expf(-x)); }
__device__ __forceinline__ float tanh_(float x) {
  float ax = fminf(fabsf(x), 15.f);
  float e = __expf(2.f * ax);
  float r = (e - 1.f) / (e + 1.f);
  return x < 0.f ? -r : r;
}

__device__ __forceinline__ u64 ald(const u64* p) {
  return __hip_atomic_load(p, __ATOMIC_RELAXED, __HIP_MEMORY_SCOPE_AGENT);
}
__device__ __forceinline__ void ast(u64* p, u64 v) {
  __hip_atomic_store(p, v, __ATOMIC_RELAXED, __HIP_MEMORY_SCOPE_AGENT);
}
__device__ __forceinline__ u32 ald32(const u32* p) {
  return __hip_atomic_load(p, __ATOMIC_RELAXED, __HIP_MEMORY_SCOPE_AGENT);
}
__device__ __forceinline__ void ast32(u32* p, u32 v) {
  __hip_atomic_store(p, v, __ATOMIC_RELAXED, __HIP_MEMORY_SCOPE_AGENT);
}

// device-scope 16B load (sc1: L2-bypass, L3-coherent); async until WAITV
#define LOADX4(dst, ptr, IMM) \
  asm volatile("global_load_dwordx4 %0, %1, off offset:" #IMM " sc1" : "=v"(dst) : "v"(ptr))
#define WAITV(N) do { \
  asm volatile("s_waitcnt vmcnt(" #N ")" ::: "memory"); \
  __builtin_amdgcn_sched_barrier(0); } while (0)
#define WAITLGKM() do { \
  asm volatile("s_waitcnt lgkmcnt(0)" ::: "memory"); \
  __builtin_amdgcn_sched_barrier(0); } while (0)

// one k-group = 4 tiles (4 k-chunks x 1KB), two row-blocks; lane-contiguous
#define IS8(r0,r1,r2,r3,r4,r5,r6,r7,p0,p1) do { \
  LOADX4(r0, p0, 0);    LOADX4(r1, p1, 0); \
  LOADX4(r2, p0, 1024); LOADX4(r3, p1, 1024); \
  LOADX4(r4, p0, 2048); LOADX4(r5, p1, 2048); \
  LOADX4(r6, p0, 3072); LOADX4(r7, p1, 3072); } while (0)

union vv { v4 u; s8 s; };
__device__ __forceinline__ s8 as_s8(v4 x) { vv t; t.u = x; return t.s; }
union uab { u64 q[2]; s8 v; };
union vf4 { v4 u; float f[4]; };
union f2u { float f[2]; u64 q; };

// ---------------- prep kernels ----------------
__global__ void prep_pack(const float* __restrict__ Wih0, const float* __restrict__ Whh0,
                          const float* __restrict__ Wih1, const float* __restrict__ Whh1,
                          const float* __restrict__ Wproj,
                          u16* __restrict__ W0C, u16* __restrict__ WIH1p,
                          u16* __restrict__ WHH0p, u16* __restrict__ WHH1p,
                          u16* __restrict__ Up) {
  int stride = gridDim.x * blockDim.x;
  int i0 = blockIdx.x * blockDim.x + threadIdx.x;
  for (int idx = i0; idx < G4 * 32; idx += stride) {
    int n = idx >> 5, k = idx & 31;
    W0C[idx] = (k < 9) ? (u16)f2bf(Wih0[n * 9 + k]) : (u16)0;
  }
  for (int idx = i0; idx < G4 * 512; idx += stride) {
    int n = idx >> 9, k = idx & 511;
    WIH1p[idx] = (u16)f2bf(Wih1[idx]);
    WHH0p[idx] = (u16)f2bf(Whh0[idx]);
    WHH1p[idx] = (u16)f2bf(Whh1[idx]);
    Up[idx]    = (u16)f2bf(Wih0[n * 9] * Wproj[k]);
  }
}

__global__ void prep_xe(const float* __restrict__ xf, const float* __restrict__ z,
                        const float* __restrict__ Wz, const float* __restrict__ bz,
                        const float* __restrict__ bproj, u16* __restrict__ xe) {
  int idx = blockIdx.x * blockDim.x + threadIdx.x;
  if (idx >= NSTEPS * B_SZ) return;
  int t = idx >> 10, b = idx & 1023;
  float zb[9];
#pragma unroll
  for (int i = 0; i < 9; i++) {
    float s = bz[i];
#pragma unroll
    for (int d = 0; d < 16; d++) s += z[b * 16 + d] * Wz[i * 16 + d];
    zb[i] = s;
  }
  __align__(16) u16 o[16];
  o[0] = (u16)f2bf(zb[0] + (t > 0 ? bproj[0] : 0.f));
#pragma unroll
  for (int e = 0; e < 8; e++) o[1 + e] = (u16)f2bf(xf[b * 512 + t * 8 + e] + zb[1 + e]);
#pragma unroll
  for (int k = 9; k < 16; k++) o[k] = 0;
  uint4* dst = (uint4*)(xe + (size_t)idx * 16);
  dst[0] = *(const uint4*)&o[0];
  dst[1] = *(const uint4*)&o[8];
}

// initial h -> TILED layout, slot 1
__global__ void prep_state(const float* __restrict__ h0in, u16* __restrict__ h0s,
                           u16* __restrict__ h1s, u32* __restrict__ flags) {
  int i = blockIdx.x * blockDim.x + threadIdx.x;
  if (i < B_SZ * H_SZ) {
    int r = i >> 9, k = i & 511;
    int ti = ((r >> 4) * 16 + (k >> 5)) * 512
           + ((r & 15) + (((k >> 3) & 3) << 4)) * 8 + (k & 7);
    h0s[524288 + ti] = (u16)f2bf(h0in[i]);
    h1s[524288 + ti] = (u16)f2bf(h0in[524288 + i]);
  }
  if (i < 256) flags[i] = 0;
}

// ---------------- main persistent kernel ----------------
struct MainParams {
  const float* y0; const float* c0;
  const float* bih0; const float* bhh0; const float* bih1; const float* bhh1;
  const float* wproj; const float* bproj;
  const u16* xe; const u16* w0c; const u16* wih1; const u16* whh0;
  const u16* whh1; const u16* up;
  u64* h0u; u64* h1u; float* ypart; u32* flags; float* out;
};

__device__ __forceinline__ f4 MFMA_(s8 a, s8 b, f4 c) {
  return __builtin_amdgcn_mfma_f32_16x16x32_bf16(a, b, c, 0, 0, 0);
}

// prologue-only: K=512 gemm, TILED h, intrinsic atomic loads (slow, runs once)
__device__ __forceinline__ void gemmK512_2(const u64* hb, int tb0, int tb1,
    const char* b0p, const char* b1p, f4 acc[4]) {
#pragma unroll
  for (int kc = 0; kc < 16; kc++) {
    uab a0; a0.q[0] = ald(hb + tb0 + kc * 128); a0.q[1] = ald(hb + tb0 + kc * 128 + 1);
    uab a1; a1.q[0] = ald(hb + tb1 + kc * 128); a1.q[1] = ald(hb + tb1 + kc * 128 + 1);
    s8 b0 = *(const s8*)(b0p + kc * 64);
    s8 b1 = *(const s8*)(b1p + kc * 64);
    acc[0] = MFMA_(a0.v, b0, acc[0]);
    acc[1] = MFMA_(a0.v, b1, acc[1]);
    acc[2] = MFMA_(a1.v, b0, acc[2]);
    acc[3] = MFMA_(a1.v, b1, acc[3]);
  }
}

// consume 8 regs (4 k-chunks x 2 row-blocks) feeding two acc sets
__device__ __forceinline__ void cons_dual8(
    v4 A0, v4 A1, v4 A2, v4 A3, v4 A4, v4 A5, v4 A6, v4 A7,
    const char* wq0, const char* wq1, const char* wp0, const char* wp1,
    f4 accQ[4], f4 accP[4]) {
#define DPAIR(x, y, OFF) do { \
    s8 bq0 = *(const s8*)(wq0 + OFF); s8 bq1 = *(const s8*)(wq1 + OFF); \
    s8 bp0 = *(const s8*)(wp0 + OFF); s8 bp1 = *(const s8*)(wp1 + OFF); \
    accQ[0] = MFMA_(x, bq0, accQ[0]); accQ[1] = MFMA_(x, bq1, accQ[1]); \
    accQ[2] = MFMA_(y, bq0, accQ[2]); accQ[3] = MFMA_(y, bq1, accQ[3]); \
    accP[0] = MFMA_(x, bp0, accP[0]); accP[1] = MFMA_(x, bp1, accP[1]); \
    accP[2] = MFMA_(y, bp0, accP[2]); accP[3] = MFMA_(y, bp1, accP[3]); } while (0)
  DPAIR(as_s8(A0), as_s8(A1), 0);
  DPAIR(as_s8(A2), as_s8(A3), 64);
  DPAIR(as_s8(A4), as_s8(A5), 128);
  DPAIR(as_s8(A6), as_s8(A7), 192);
#undef DPAIR
}

// per-wave quarter wait: lanes 0..15 poll the 16 producer flags of quarter q.
__device__ __forceinline__ void qwait(const u32* flagc, int q, u32 target, int lane) {
  int spins = 0;
  for (;;) {
    u32 v = (lane < 16) ? ald32(&flagc[q * 16 + lane]) : target;
    if (__all(v >= target)) break;
    __builtin_amdgcn_s_sleep(1);
    if (++spins > (1 << 18)) break;   // fail-safe: never hang
  }
  __builtin_amdgcn_sched_barrier(0);
  asm volatile("" ::: "memory");
}

// arrival: own stores drained -> block-wide join -> bump own flag to phase#
__device__ __forceinline__ void arrive(u32* flagc, int js, int tid, u32 val) {
  asm volatile("s_waitcnt vmcnt(0)" ::: "memory");
  __syncthreads();
  if (tid == 0) ast32(&flagc[js], val);
}

struct LaneCtx { int mb0, grp, pp, jl, hlf; };

// bias, lane^8 gate exchange (i,g <-> f,o), cell math, write h (bf16) to LDS stage
__device__ __forceinline__ void cell_update(f4 acc[4], const float bias[2], float cr[2][2],
    u16* __restrict__ hst, int lbase, const LaneCtx& L, float hval[2][2]) {
#pragma unroll
  for (int m = 0; m < 2; m++)
#pragma unroll
    for (int n = 0; n < 2; n++)
#pragma unroll
      for (int r = 0; r < 4; r++) acc[m * 2 + n][r] += bias[n];
  f4 rx[4];
#pragma unroll
  for (int q = 0; q < 4; q++)
#pragma unroll
    for (int r = 0; r < 4; r++) rx[q][r] = __shfl_xor(acc[q][r], 8);
#pragma unroll
  for (int mtl = 0; mtl < 2; mtl++) {
#pragma unroll
    for (int q = 0; q < 2; q++) {
      int r = L.hlf * 2 + q;
      float iv = L.hlf ? rx[mtl * 2 + 0][r] : acc[mtl * 2 + 0][r];
      float fv = L.hlf ? acc[mtl * 2 + 0][r] : rx[mtl * 2 + 0][r];
      float gv = L.hlf ? rx[mtl * 2 + 1][r] : acc[mtl * 2 + 1][r];
      float ov = L.hlf ? acc[mtl * 2 + 1][r] : rx[mtl * 2 + 1][r];
      float c2 = sigm(fv) * cr[mtl][q] + sigm(iv) * tanh_(gv);
      float hv = sigm(ov) * tanh_(c2);
      cr[mtl][q] = c2;
      hval[mtl][q] = hv;
      int lrow = lbase + mtl * 16 + L.grp * 4 + r;
      hst[lrow * 8 + L.jl] = (u16)f2bf(hv);
    }
  }
}

__global__ __launch_bounds__(512, 2) void lstm_main(MainParams p) {
  extern __shared__ char lds[];
  float* yrow = (float*)(lds + LDS_YROW);
  u16* hst = (u16*)(lds + LDS_HST);

  const int bx = blockIdx.x, chunk = bx >> 6, js = bx & 63;
  const int tid = threadIdx.x, lane = tid & 63, wid = tid >> 6;

  { // stage weight slices into LDS once
    int n = tid & 31, part = tid >> 5;
    int ng = ((n >> 3) << 9) + js * 8 + (n & 7);
#define STAGE(MATP, LOFF) do { \
    const u32* s_ = (const u32*)(p.MATP + (size_t)ng * 512); \
    u32* d_ = (u32*)(lds + LOFF + n * WSTRIDE + part * 64); \
    _Pragma("unroll") for (int q = 0; q < 16; q++) d_[q] = s_[part * 16 + q]; } while (0)
    STAGE(wih1, LDS_WA1);
    STAGE(whh0, LDS_WA0);
    STAGE(whh1, LDS_WB1);
    STAGE(up,   LDS_WBU);
#undef STAGE
    const u32* s0 = (const u32*)(p.w0c + (size_t)ng * 32);
    u32* d0 = (u32*)(lds + LDS_W0C + n * 64);
    d0[part] = s0[part];
    if (tid < 256) yrow[tid] = p.y0[chunk * 256 + tid];
  }

  LaneCtx L;
  L.grp = lane >> 4; L.pp = lane & 15; L.jl = lane & 7; L.hlf = (lane >> 3) & 1;
  L.mb0 = chunk * 256 + wid * 32;
  const int lbase = wid * 32;
  const int j = js * 8 + L.jl;
  const int rb0 = chunk * 16 + wid * 2;              // row-block of arow0 set
  const int aoff0 = rb0 * 16384 + lane * 16;         // TILED byte offset
  const int aoff1 = aoff0 + 16384;                   // next row-block
  const int tb0 = rb0 * 2048 + lane * 2;             // u64 idx (prologue)
  const int tb1 = tb0 + 2048;
  // prologue store slot (tid<256): row r = chunk*256+tid, kblk = js>>2
  const int pst = (chunk * 16 + (tid >> 4)) * 2048 + (js >> 2) * 128
                + ((tid & 15) + ((js & 3) << 4)) * 2;
  // per-wave store base (lane<32: local row rl = lbase+lane)
  const int pwb = chunk * 16 * 2048 + (js >> 2) * 128 + ((js & 3) << 4) * 2;

  float bias0[2], bias1[2];
#pragma unroll
  for (int ntl = 0; ntl < 2; ntl++) {
    int n = ntl * 16 + L.pp;
    int ng = ((n >> 3) << 9) + js * 8 + (n & 7);
    bias0[ntl] = p.bih0[ng] + p.bhh0[ng];
    bias1[ntl] = p.bih1[ng] + p.bhh1[ng];
  }
  float wpj = p.wproj[j];
  float bpj = p.bproj[0];

  float c0r[2][2], c1r[2][2];
#pragma unroll
  for (int mtl = 0; mtl < 2; mtl++)
#pragma unroll
    for (int q = 0; q < 2; q++) {
      int row = L.mb0 + mtl * 16 + L.grp * 4 + L.hlf * 2 + q;
      c0r[mtl][q] = p.c0[row * 512 + j];
      c1r[mtl][q] = p.c0[524288 + row * 512 + j];
    }

  u32* flagc = p.flags + chunk * 64;
  const char* wA1_0 = lds + LDS_WA1 + L.pp * WSTRIDE + L.grp * 16;
  const char* wA1_1 = lds + LDS_WA1 + (16 + L.pp) * WSTRIDE + L.grp * 16;
  const char* wA0_0 = lds + LDS_WA0 + L.pp * WSTRIDE + L.grp * 16;
  const char* wA0_1 = lds + LDS_WA0 + (16 + L.pp) * WSTRIDE + L.grp * 16;
  const char* wB1_0 = lds + LDS_WB1 + L.pp * WSTRIDE + L.grp * 16;
  const char* wB1_1 = lds + LDS_WB1 + (16 + L.pp) * WSTRIDE + L.grp * 16;
  const char* wBU_0 = lds + LDS_WBU + L.pp * WSTRIDE + L.grp * 16;
  const char* wBU_1 = lds + LDS_WBU + (16 + L.pp) * WSTRIDE + L.grp * 16;
  const char* w0c_0 = lds + LDS_W0C + L.pp * 64 + L.grp * 16;
  const char* w0c_1 = lds + LDS_W0C + (16 + L.pp) * 64 + L.grp * 16;

  const int rot = js & 3;
  const int q0 = (rot + 0) & 3, q1 = (rot + 1) & 3;
  const int q2 = (rot + 2) & 3, q3 = (rot + 3) & 3;
  const int g0 = q0 * 4096, g1 = q1 * 4096, g2 = q2 * 4096, g3 = q3 * 4096;
  const int o0 = g0 >> 4, o1 = g1 >> 4, o2 = g2 >> 4, o3 = g3 >> 4;

  __syncthreads();

  f4 accP[4] = {{0,0,0,0},{0,0,0,0},{0,0,0,0},{0,0,0,0}};   // gates0 accum
  f4 accQ[4] = {{0,0,0,0},{0,0,0,0},{0,0,0,0},{0,0,0,0}};   // gates1 accum

  // ===== prologue: gates0(0) = Whh0 h0(-1) + chunk0(y0) ; carry Whh1 h1(-1) =====
  gemmK512_2(p.h0u + 131072, tb0, tb1, wA0_0, wA0_1, accP);
  {
    s8 a0 = {0,0,0,0,0,0,0,0}, a1 = {0,0,0,0,0,0,0,0};
    if (L.grp < 2) {
      const char* xb = (const char*)p.xe;   // t = 0
      a0 = *(const s8*)(xb + (L.mb0 + L.pp) * 32 + L.grp * 16);
      a1 = *(const s8*)(xb + (L.mb0 + 16 + L.pp) * 32 + L.grp * 16);
      if (L.grp == 0) {
        a0[0] = f2bf(bf2f(a0[0]) + yrow[wid * 32 + L.pp]);
        a1[0] = f2bf(bf2f(a1[0]) + yrow[wid * 32 + 16 + L.pp]);
      }
    }
    s8 b0 = *(const s8*)(w0c_0);
    s8 b1 = *(const s8*)(w0c_1);
    accP[0] = MFMA_(a0, b0, accP[0]);
    accP[1] = MFMA_(a0, b1, accP[1]);
    accP[2] = MFMA_(a1, b0, accP[2]);
    accP[3] = MFMA_(a1, b1, accP[3]);
  }
  {
    float hd[2][2];
    cell_update(accP, bias0, c0r, hst, lbase, L, hd);
  }
  gemmK512_2(p.h1u + 131072, tb0, tb1, wB1_0, wB1_1, accQ);  // Whh1 h1(-1) carry
  __syncthreads();
  if (tid < 256) {
    const u64* src = (const u64*)&hst[tid * 8];
    u64* dst = p.h0u + pst;   // slot 0 = h0(0)
    ast(dst, src[0]);
    ast(dst + 1, src[1]);
  }
  arrive(flagc, js, tid, 1u);
#pragma unroll
  for (int q = 0; q < 4; q++) accP[q] = (f4){0, 0, 0, 0};

  v4 A0, A1, A2, A3, A4, A5, A6, A7;
  v4 C0, C1, C2, C3, C4, C5, C6, C7;

  for (int t = 0; t < NSTEPS; t++) {
    // ===== phase A: read h0(t); gates1(t) += Wih1 h0 ; gates0(t+1) += Whh0 h0 =====
    {
      const u32 tg = (u32)(2 * t + 1);
      const char* hb = (const char*)p.h0u + (size_t)(t & 1) * 1048576;
      const char* pa0 = hb + aoff0;
      const char* pa1 = hb + aoff1;
      qwait(flagc, q0, tg, lane);
      IS8(A0,A1,A2,A3,A4,A5,A6,A7, pa0 + g0, pa1 + g0);
      qwait(flagc, q1, tg, lane);
      IS8(C0,C1,C2,C3,C4,C5,C6,C7, pa0 + g1, pa1 + g1);
      WAITV(8);
      cons_dual8(A0,A1,A2,A3,A4,A5,A6,A7, wA1_0+o0, wA1_1+o0, wA0_0+o0, wA0_1+o0, accQ, accP);
      qwait(flagc, q2, tg, lane);
      IS8(A0,A1,A2,A3,A4,A5,A6,A7, pa0 + g2, pa1 + g2);
      WAITV(8);
      cons_dual8(C0,C1,C2,C3,C4,C5,C6,C7, wA1_0+o1, wA1_1+o1, wA0_0+o1, wA0_1+o1, accQ, accP);
      qwait(flagc, q3, tg, lane);
      IS8(C0,C1,C2,C3,C4,C5,C6,C7, pa0 + g3, pa1 + g3);
      WAITV(8);
      cons_dual8(A0,A1,A2,A3,A4,A5,A6,A7, wA1_0+o2, wA1_1+o2, wA0_0+o2, wA0_1+o2, accQ, accP);
      WAITV(0);
      cons_dual8(C0,C1,C2,C3,C4,C5,C6,C7, wA1_0+o3, wA1_1+o3, wA0_0+o3, wA0_1+o3, accQ, accP);

      float hval[2][2];
      cell_update(accQ, bias1, c1r, hst, lbase, L, hval);
      // per-wave EARLY store of own 32 rows (wave-local hst; no block sync needed)
      WAITLGKM();
      if (lane < 32) {
        int rl = lbase + lane;
        const u64* src = (const u64*)&hst[rl * 8];
        u64* dst = p.h1u + (size_t)(t & 1) * 131072
                 + pwb + (rl >> 4) * 2048 + (rl & 15) * 2;
        ast(dst, src[0]);
        ast(dst + 1, src[1]);
      }
      // proj partials -> ypart[js][row]: paired 8B stores tiling exact 64B lines
      {
        float py[2][2];
#pragma unroll
        for (int mtl = 0; mtl < 2; mtl++)
#pragma unroll
          for (int q = 0; q < 2; q++) {
            float s = hval[mtl][q] * wpj;
            s += __shfl_xor(s, 1);
            s += __shfl_xor(s, 2);
            s += __shfl_xor(s, 4);
            py[mtl][q] = s;
          }
        if (L.jl == 0) {
#pragma unroll
          for (int mtl = 0; mtl < 2; mtl++) {
            int row = L.mb0 + mtl * 16 + L.grp * 4 + L.hlf * 2;
            f2u u; u.f[0] = py[mtl][0]; u.f[1] = py[mtl][1];
            ast((u64*)((char*)p.ypart + (size_t)js * 4096 + (size_t)row * 4), u.q);
          }
        }
      }
      arrive(flagc, js, tid, tg + 1);
#pragma unroll
      for (int q = 0; q < 4; q++) accQ[q] = (f4){0, 0, 0, 0};
    }

    // ===== phase B: read h1(t); gates1(t+1) += Whh1 h1 ; gates0(t+1) += U h1 =====
    {
      const u32 tg = (u32)(2 * t + 2);
      const char* hb = (const char*)p.h1u + (size_t)(t & 1) * 1048576;
      const char* pb0 = hb + aoff0;
      const char* pb1 = hb + aoff1;
      qwait(flagc, q0, tg, lane);
      IS8(A0,A1,A2,A3,A4,A5,A6,A7, pb0 + g0, pb1 + g0);
      qwait(flagc, q1, tg, lane);
      IS8(C0,C1,C2,C3,C4,C5,C6,C7, pb0 + g1, pb1 + g1);
      WAITV(8);
      cons_dual8(A0,A1,A2,A3,A4,A5,A6,A7, wB1_0+o0, wB1_1+o0, wBU_0+o0, wBU_1+o0, accQ, accP);
      qwait(flagc, q2, tg, lane);
      IS8(A0,A1,A2,A3,A4,A5,A6,A7, pb0 + g2, pb1 + g2);
      WAITV(8);
      cons_dual8(C0,C1,C2,C3,C4,C5,C6,C7, wB1_0+o1, wB1_1+o1, wBU_0+o1, wBU_1+o1, accQ, accP);
      qwait(flagc, q3, tg, lane);   // after this, ALL 64 producers of A(t) arrived
      IS8(C0,C1,C2,C3,C4,C5,C6,C7, pb0 + g3, pb1 + g3);
      // wave-0: y-reduce of step t (gated by 4th qwait). WAITV(0) over-drains wave 0 only.
      if (tid < 64) {
        v4 Yv;
        const char* yq = (const char*)p.ypart + (size_t)lane * 4096
                       + (size_t)(chunk * 256 + js * 4) * 4;
        LOADX4(Yv, yq, 0);
        WAITV(0);
        vf4 w; w.u = Yv;
        float s0 = w.f[0], s1 = w.f[1], s2 = w.f[2], s3 = w.f[3];
#pragma unroll
        for (int m = 1; m < 64; m <<= 1) {
          s0 += __shfl_xor(s0, m);
          s1 += __shfl_xor(s1, m);
          s2 += __shfl_xor(s2, m);
          s3 += __shfl_xor(s3, m);
        }
        if (lane == 0) {
          int rb = chunk * 256 + js * 4;
          p.out[(rb + 0) * 64 + t] = s0 + bpj;
          p.out[(rb + 1) * 64 + t] = s1 + bpj;
          p.out[(rb + 2) * 64 + t] = s2 + bpj;
          p.out[(rb + 3) * 64 + t] = s3 + bpj;
        }
      }
      WAITV(8);
      cons_dual8(A0,A1,A2,A3,A4,A5,A6,A7, wB1_0+o2, wB1_1+o2, wBU_0+o2, wBU_1+o2, accQ, accP);
      WAITV(0);
      cons_dual8(C0,C1,C2,C3,C4,C5,C6,C7, wB1_0+o3, wB1_1+o3, wBU_0+o3, wBU_1+o3, accQ, accP);

      // chunk0 of gates0(t+1): exo+z(+bproj) const part (y folded into U + xe slot0)
      {
        int tn = (t < 63) ? t + 1 : 63;
        s8 a0 = {0,0,0,0,0,0,0,0}, a1 = {0,0,0,0,0,0,0,0};
        if (L.grp < 2) {
          const char* xb = (const char*)p.xe + (size_t)tn * 32768;
          a0 = *(const s8*)(xb + (L.mb0 + L.pp) * 32 + L.grp * 16);
          a1 = *(const s8*)(xb + (L.mb0 + 16 + L.pp) * 32 + L.grp * 16);
        }
        s8 b0 = *(const s8*)(w0c_0);
        s8 b1 = *(const s8*)(w0c_1);
        accP[0] = MFMA_(a0, b0, accP[0]);
        accP[1] = MFMA_(a0, b1, accP[1]);
        accP[2] = MFMA_(a1, b0, accP[2]);
        accP[3] = MFMA_(a1, b1, accP[3]);
      }
      float hd[2][2];
      cell_update(accP, bias0, c0r, hst, lbase, L, hd);
      // per-wave EARLY store of own 32 rows
      WAITLGKM();
      if (lane < 32) {
        int rl = lbase + lane;
        const u64* src = (const u64*)&hst[rl * 8];
        u64* dst = p.h0u + (size_t)((t + 1) & 1) * 131072
                 + pwb + (rl >> 4) * 2048 + (rl & 15) * 2;
        ast(dst, src[0]);
        ast(dst + 1, src[1]);
      }
      arrive(flagc, js, tid, tg + 1);
#pragma unroll
      for (int q = 0; q < 4; q++) accP[q] = (f4){0, 0, 0, 0};
    }
  }
}

extern "C" void kernel_launch(void* const* d_in, const int* in_sizes, int n_in,
                              void* d_out, int out_size, void* d_ws, size_t ws_size,
                              hipStream_t stream) {
  const float* y0   = (const float*)d_in[0];
  const float* xf   = (const float*)d_in[1];
  const float* h0   = (const float*)d_in[2];
  const float* c0   = (const float*)d_in[3];
  const float* z    = (const float*)d_in[4];
  const float* Wih0 = (const float*)d_in[5];
  const float* Whh0 = (const float*)d_in[6];
  const float* bih0 = (const float*)d_in[7];
  const float* bhh0 = (const float*)d_in[8];
  const float* Wih1 = (const float*)d_in[9];
  const float* Whh1 = (const float*)d_in[10];
  const float* bih1 = (const float*)d_in[11];
  const float* bhh1 = (const float*)d_in[12];
  const float* Wpr  = (const float*)d_in[13];
  const float* bpr  = (const float*)d_in[14];
  const float* Wz   = (const float*)d_in[15];
  const float* bz   = (const float*)d_in[16];

  if (ws_size < WS_NEEDED) return;
  char* ws = (char*)d_ws;
  u16* xe    = (u16*)(ws + WS_XE);
  u16* w0c   = (u16*)(ws + WS_W0C);
  u16* wih1  = (u16*)(ws + WS_WIH1);
  u16* whh0  = (u16*)(ws + WS_WHH0);
  u16* whh1  = (u16*)(ws + WS_WHH1);
  u16* up    = (u16*)(ws + WS_UP);
  u64* h0u   = (u64*)(ws + WS_H0S);
  u64* h1u   = (u64*)(ws + WS_H1S);
  float* ypart = (float*)(ws + WS_YPART);
  u32* flags = (u32*)(ws + WS_FLAGS);

  prep_pack<<<1024, 256, 0, stream>>>(Wih0, Whh0, Wih1, Whh1, Wpr,
                                      w0c, wih1, whh0, whh1, up);
  prep_xe<<<256, 256, 0, stream>>>(xf, z, Wz, bz, bpr, xe);
  prep_state<<<2048, 256, 0, stream>>>(h0, (u16*)h0u, (u16*)h1u, flags);

  MainParams prm;
  prm.y0 = y0; prm.c0 = c0;
  prm.bih0 = bih0; prm.bhh0 = bhh0; prm.bih1 = bih1; prm.bhh1 = bhh1;
  prm.wproj = Wpr; prm.bproj = bpr;
  prm.xe = xe; prm.w0c = w0c; prm.wih1 = wih1; prm.whh0 = whh0;
  prm.whh1 = whh1; prm.up = up;
  prm.h0u = h0u; prm.h1u = h1u; prm.ypart = ypart; prm.flags = flags;
  prm.out = (float*)d_out;

  hipFuncSetAttribute((const void*)lstm_main, hipFuncAttributeMaxDynamicSharedMemorySize, LDS_TOTAL);
  void* args[] = { &prm };
  hipLaunchCooperativeKernel((void*)lstm_main, dim3(256), dim3(512), args, LDS_TOTAL, stream);
}

// Round 15
// 1059.724 us; speedup vs baseline: 1.5383x; 1.0888x over previous
//
#include <hip/hip_runtime.h>

typedef unsigned int u32;
typedef unsigned short u16;
typedef unsigned long long u64;
typedef short s8 __attribute__((ext_vector_type(8)));   // 8 x bf16 (as i16)
typedef float f4 __attribute__((ext_vector_type(4)));
typedef u32 v4 __attribute__((ext_vector_type(4)));     // 16B asm load payload

#define B_SZ   1024
#define H_SZ   512
#define G4     2048
#define NSTEPS 64

// ws layout (bytes)
#define WS_XE     0u          // [64][1024][16] bf16  = 2097152
#define WS_W0C    2097152u    // [2048][32]  bf16     = 131072
#define WS_WIH1   2228224u    // [2048][512] bf16     = 2097152
#define WS_WHH0   4325376u    // [2048][512] bf16     = 2097152
#define WS_WHH1   6422528u    // [2048][512] bf16     = 2097152
#define WS_UP     8519680u    // [2048][512] bf16     = 2097152  (U = wih0[:,0] x wproj)
#define WS_H0S    10616832u   // [2][TILED 1024x512] bf16 = 2097152
#define WS_H1S    12713984u   // [2][TILED 1024x512] bf16 = 2097152
#define WS_YPART  14811136u   // [64 js][1024 rows] f32 = 262144
#define WS_FLAGS  15335424u   // [4][64] u32          = 1024
#define WS_NEEDED 15336448u

// h TILED layout: tile(rblk=r>>4, kblk=k>>5) = 1KB at rblk*16384 + kblk*1024;
// inner byte = lane*16, lane = (r&15) + ((k>>3)&3)*16  == MFMA A-frag mapping.
// Producer js writes ONLY kblk = js>>2  =>  k-quarter q = js>>4 has exactly
// 16 producers js in [16q, 16q+16). Consumers gate per-quarter (qwait),
// consuming their OWN quarter first (rot = js>>4).

// LDS layout (bytes); weight row stride 1040 (520 bf16: 2-way bank alias = free)
#define WSTRIDE   1040
#define LDS_WA1   0        // W_ih1 slice  32 x 1040
#define LDS_WA0   33280    // W_hh0 slice
#define LDS_WB1   66560    // W_hh1 slice
#define LDS_WBU   99840    // U slice
#define LDS_W0C   133120   // chunk0 weights 32 x 64B
#define LDS_YROW  135168   // f32[256]
#define LDS_HST   136192   // u16[256][8]
#define LDS_TOTAL 140288

__device__ __forceinline__ float bf2f(short s) {
  u32 u = ((u32)(u16)s) << 16; float f; __builtin_memcpy(&f, &u, 4); return f;
}
__device__ __forceinline__ short f2bf(float f) {
  u32 u; __builtin_memcpy(&u, &f, 4);
  u = (u + 0x7fffu + ((u >> 16) & 1u)) >> 16; return (short)u;
}
__device__ __forceinline__ float sigm(float x) { return 1.f / (1.f + __expf(-x)); }
__device__ __forceinline__ float tanh_(float x) {
  float ax = fminf(fabsf(x), 15.f);
  float e = __expf(2.f * ax);
  float r = (e - 1.f) / (e + 1.f);
  return x < 0.f ? -r : r;
}

__device__ __forceinline__ u64 ald(const u64* p) {
  return __hip_atomic_load(p, __ATOMIC_RELAXED, __HIP_MEMORY_SCOPE_AGENT);
}
__device__ __forceinline__ void ast(u64* p, u64 v) {
  __hip_atomic_store(p, v, __ATOMIC_RELAXED, __HIP_MEMORY_SCOPE_AGENT);
}
__device__ __forceinline__ u32 ald32(const u32* p) {
  return __hip_atomic_load(p, __ATOMIC_RELAXED, __HIP_MEMORY_SCOPE_AGENT);
}
__device__ __forceinline__ void ast32(u32* p, u32 v) {
  __hip_atomic_store(p, v, __ATOMIC_RELAXED, __HIP_MEMORY_SCOPE_AGENT);
}

// device-scope 16B load (sc1: L2-bypass, L3-coherent); async until WAITV
#define LOADX4(dst, ptr, IMM) \
  asm volatile("global_load_dwordx4 %0, %1, off offset:" #IMM " sc1" : "=v"(dst) : "v"(ptr))
#define WAITV(N) do { \
  asm volatile("s_waitcnt vmcnt(" #N ")" ::: "memory"); \
  __builtin_amdgcn_sched_barrier(0); } while (0)
#define WAITLGKM() do { \
  asm volatile("s_waitcnt lgkmcnt(0)" ::: "memory"); \
  __builtin_amdgcn_sched_barrier(0); } while (0)

// one k-group = 4 tiles (4 k-chunks x 1KB), two row-blocks; lane-contiguous
#define IS8(r0,r1,r2,r3,r4,r5,r6,r7,p0,p1) do { \
  LOADX4(r0, p0, 0);    LOADX4(r1, p1, 0); \
  LOADX4(r2, p0, 1024); LOADX4(r3, p1, 1024); \
  LOADX4(r4, p0, 2048); LOADX4(r5, p1, 2048); \
  LOADX4(r6, p0, 3072); LOADX4(r7, p1, 3072); } while (0)

union vv { v4 u; s8 s; };
__device__ __forceinline__ s8 as_s8(v4 x) { vv t; t.u = x; return t.s; }
union uab { u64 q[2]; s8 v; };
union vf4 { v4 u; float f[4]; };
union f2u { float f[2]; u64 q; };

// ---------------- prep kernels ----------------
__global__ void prep_pack(const float* __restrict__ Wih0, const float* __restrict__ Whh0,
                          const float* __restrict__ Wih1, const float* __restrict__ Whh1,
                          const float* __restrict__ Wproj,
                          u16* __restrict__ W0C, u16* __restrict__ WIH1p,
                          u16* __restrict__ WHH0p, u16* __restrict__ WHH1p,
                          u16* __restrict__ Up) {
  int stride = gridDim.x * blockDim.x;
  int i0 = blockIdx.x * blockDim.x + threadIdx.x;
  for (int idx = i0; idx < G4 * 32; idx += stride) {
    int n = idx >> 5, k = idx & 31;
    W0C[idx] = (k < 9) ? (u16)f2bf(Wih0[n * 9 + k]) : (u16)0;
  }
  for (int idx = i0; idx < G4 * 512; idx += stride) {
    int n = idx >> 9, k = idx & 511;
    WIH1p[idx] = (u16)f2bf(Wih1[idx]);
    WHH0p[idx] = (u16)f2bf(Whh0[idx]);
    WHH1p[idx] = (u16)f2bf(Whh1[idx]);
    Up[idx]    = (u16)f2bf(Wih0[n * 9] * Wproj[k]);
  }
}

__global__ void prep_xe(const float* __restrict__ xf, const float* __restrict__ z,
                        const float* __restrict__ Wz, const float* __restrict__ bz,
                        const float* __restrict__ bproj, u16* __restrict__ xe) {
  int idx = blockIdx.x * blockDim.x + threadIdx.x;
  if (idx >= NSTEPS * B_SZ) return;
  int t = idx >> 10, b = idx & 1023;
  float zb[9];
#pragma unroll
  for (int i = 0; i < 9; i++) {
    float s = bz[i];
#pragma unroll
    for (int d = 0; d < 16; d++) s += z[b * 16 + d] * Wz[i * 16 + d];
    zb[i] = s;
  }
  __align__(16) u16 o[16];
  o[0] = (u16)f2bf(zb[0] + (t > 0 ? bproj[0] : 0.f));
#pragma unroll
  for (int e = 0; e < 8; e++) o[1 + e] = (u16)f2bf(xf[b * 512 + t * 8 + e] + zb[1 + e]);
#pragma unroll
  for (int k = 9; k < 16; k++) o[k] = 0;
  uint4* dst = (uint4*)(xe + (size_t)idx * 16);
  dst[0] = *(const uint4*)&o[0];
  dst[1] = *(const uint4*)&o[8];
}

// initial h -> TILED layout, slot 1
__global__ void prep_state(const float* __restrict__ h0in, u16* __restrict__ h0s,
                           u16* __restrict__ h1s, u32* __restrict__ flags) {
  int i = blockIdx.x * blockDim.x + threadIdx.x;
  if (i < B_SZ * H_SZ) {
    int r = i >> 9, k = i & 511;
    int ti = ((r >> 4) * 16 + (k >> 5)) * 512
           + ((r & 15) + (((k >> 3) & 3) << 4)) * 8 + (k & 7);
    h0s[524288 + ti] = (u16)f2bf(h0in[i]);
    h1s[524288 + ti] = (u16)f2bf(h0in[524288 + i]);
  }
  if (i < 256) flags[i] = 0;
}

// ---------------- main persistent kernel ----------------
struct MainParams {
  const float* y0; const float* c0;
  const float* bih0; const float* bhh0; const float* bih1; const float* bhh1;
  const float* wproj; const float* bproj;
  const u16* xe; const u16* w0c; const u16* wih1; const u16* whh0;
  const u16* whh1; const u16* up;
  u64* h0u; u64* h1u; float* ypart; u32* flags; float* out;
};

__device__ __forceinline__ f4 MFMA_(s8 a, s8 b, f4 c) {
  return __builtin_amdgcn_mfma_f32_16x16x32_bf16(a, b, c, 0, 0, 0);
}

// prologue-only: K=512 gemm, TILED h, intrinsic atomic loads (slow, runs once)
__device__ __forceinline__ void gemmK512_2(const u64* hb, int tb0, int tb1,
    const char* b0p, const char* b1p, f4 acc[4]) {
#pragma unroll
  for (int kc = 0; kc < 16; kc++) {
    uab a0; a0.q[0] = ald(hb + tb0 + kc * 128); a0.q[1] = ald(hb + tb0 + kc * 128 + 1);
    uab a1; a1.q[0] = ald(hb + tb1 + kc * 128); a1.q[1] = ald(hb + tb1 + kc * 128 + 1);
    s8 b0 = *(const s8*)(b0p + kc * 64);
    s8 b1 = *(const s8*)(b1p + kc * 64);
    acc[0] = MFMA_(a0.v, b0, acc[0]);
    acc[1] = MFMA_(a0.v, b1, acc[1]);
    acc[2] = MFMA_(a1.v, b0, acc[2]);
    acc[3] = MFMA_(a1.v, b1, acc[3]);
  }
}

// consume 8 regs (4 k-chunks x 2 row-blocks) feeding two acc sets
__device__ __forceinline__ void cons_dual8(
    v4 A0, v4 A1, v4 A2, v4 A3, v4 A4, v4 A5, v4 A6, v4 A7,
    const char* wq0, const char* wq1, const char* wp0, const char* wp1,
    f4 accQ[4], f4 accP[4]) {
#define DPAIR(x, y, OFF) do { \
    s8 bq0 = *(const s8*)(wq0 + OFF); s8 bq1 = *(const s8*)(wq1 + OFF); \
    s8 bp0 = *(const s8*)(wp0 + OFF); s8 bp1 = *(const s8*)(wp1 + OFF); \
    accQ[0] = MFMA_(x, bq0, accQ[0]); accQ[1] = MFMA_(x, bq1, accQ[1]); \
    accQ[2] = MFMA_(y, bq0, accQ[2]); accQ[3] = MFMA_(y, bq1, accQ[3]); \
    accP[0] = MFMA_(x, bp0, accP[0]); accP[1] = MFMA_(x, bp1, accP[1]); \
    accP[2] = MFMA_(y, bp0, accP[2]); accP[3] = MFMA_(y, bp1, accP[3]); } while (0)
  DPAIR(as_s8(A0), as_s8(A1), 0);
  DPAIR(as_s8(A2), as_s8(A3), 64);
  DPAIR(as_s8(A4), as_s8(A5), 128);
  DPAIR(as_s8(A6), as_s8(A7), 192);
#undef DPAIR
}

// per-wave quarter wait: lanes 0..15 poll the 16 producer flags of quarter q.
__device__ __forceinline__ void qwait(const u32* flagc, int q, u32 target, int lane) {
  int spins = 0;
  for (;;) {
    u32 v = (lane < 16) ? ald32(&flagc[q * 16 + lane]) : target;
    if (__all(v >= target)) break;
    __builtin_amdgcn_s_sleep(1);
    if (++spins > (1 << 18)) break;   // fail-safe: never hang
  }
  __builtin_amdgcn_sched_barrier(0);
  asm volatile("" ::: "memory");
}

// arrival: own stores drained -> block-wide join -> bump own flag to phase#
__device__ __forceinline__ void arrive(u32* flagc, int js, int tid, u32 val) {
  asm volatile("s_waitcnt vmcnt(0)" ::: "memory");
  __syncthreads();
  if (tid == 0) ast32(&flagc[js], val);
}

struct LaneCtx { int mb0, grp, pp, jl, hlf; };

// bias, lane^8 gate exchange (i,g <-> f,o), cell math, write h (bf16) to LDS stage
__device__ __forceinline__ void cell_update(f4 acc[4], const float bias[2], float cr[2][2],
    u16* __restrict__ hst, int lbase, const LaneCtx& L, float hval[2][2]) {
#pragma unroll
  for (int m = 0; m < 2; m++)
#pragma unroll
    for (int n = 0; n < 2; n++)
#pragma unroll
      for (int r = 0; r < 4; r++) acc[m * 2 + n][r] += bias[n];
  f4 rx[4];
#pragma unroll
  for (int q = 0; q < 4; q++)
#pragma unroll
    for (int r = 0; r < 4; r++) rx[q][r] = __shfl_xor(acc[q][r], 8);
#pragma unroll
  for (int mtl = 0; mtl < 2; mtl++) {
#pragma unroll
    for (int q = 0; q < 2; q++) {
      int r = L.hlf * 2 + q;
      float iv = L.hlf ? rx[mtl * 2 + 0][r] : acc[mtl * 2 + 0][r];
      float fv = L.hlf ? acc[mtl * 2 + 0][r] : rx[mtl * 2 + 0][r];
      float gv = L.hlf ? rx[mtl * 2 + 1][r] : acc[mtl * 2 + 1][r];
      float ov = L.hlf ? acc[mtl * 2 + 1][r] : rx[mtl * 2 + 1][r];
      float c2 = sigm(fv) * cr[mtl][q] + sigm(iv) * tanh_(gv);
      float hv = sigm(ov) * tanh_(c2);
      cr[mtl][q] = c2;
      hval[mtl][q] = hv;
      int lrow = lbase + mtl * 16 + L.grp * 4 + r;
      hst[lrow * 8 + L.jl] = (u16)f2bf(hv);
    }
  }
}

__global__ __launch_bounds__(512, 2) void lstm_main(MainParams p) {
  extern __shared__ char lds[];
  float* yrow = (float*)(lds + LDS_YROW);
  u16* hst = (u16*)(lds + LDS_HST);

  const int bx = blockIdx.x, chunk = bx >> 6, js = bx & 63;
  const int tid = threadIdx.x, lane = tid & 63, wid = tid >> 6;

  { // stage weight slices into LDS once
    int n = tid & 31, part = tid >> 5;
    int ng = ((n >> 3) << 9) + js * 8 + (n & 7);
#define STAGE(MATP, LOFF) do { \
    const u32* s_ = (const u32*)(p.MATP + (size_t)ng * 512); \
    u32* d_ = (u32*)(lds + LOFF + n * WSTRIDE + part * 64); \
    _Pragma("unroll") for (int q = 0; q < 16; q++) d_[q] = s_[part * 16 + q]; } while (0)
    STAGE(wih1, LDS_WA1);
    STAGE(whh0, LDS_WA0);
    STAGE(whh1, LDS_WB1);
    STAGE(up,   LDS_WBU);
#undef STAGE
    const u32* s0 = (const u32*)(p.w0c + (size_t)ng * 32);
    u32* d0 = (u32*)(lds + LDS_W0C + n * 64);
    d0[part] = s0[part];
    if (tid < 256) yrow[tid] = p.y0[chunk * 256 + tid];
  }

  LaneCtx L;
  L.grp = lane >> 4; L.pp = lane & 15; L.jl = lane & 7; L.hlf = (lane >> 3) & 1;
  L.mb0 = chunk * 256 + wid * 32;
  const int lbase = wid * 32;
  const int j = js * 8 + L.jl;
  const int rb0 = chunk * 16 + wid * 2;              // row-block of arow0 set
  const int aoff0 = rb0 * 16384 + lane * 16;         // TILED byte offset
  const int aoff1 = aoff0 + 16384;                   // next row-block
  const int tb0 = rb0 * 2048 + lane * 2;             // u64 idx (prologue)
  const int tb1 = tb0 + 2048;
  // prologue store slot (tid<256): row r = chunk*256+tid, kblk = js>>2
  const int pst = (chunk * 16 + (tid >> 4)) * 2048 + (js >> 2) * 128
                + ((tid & 15) + ((js & 3) << 4)) * 2;
  // per-wave store base (lane<32: local row rl = lbase+lane)
  const int pwb = chunk * 16 * 2048 + (js >> 2) * 128 + ((js & 3) << 4) * 2;

  float bias0[2], bias1[2];
#pragma unroll
  for (int ntl = 0; ntl < 2; ntl++) {
    int n = ntl * 16 + L.pp;
    int ng = ((n >> 3) << 9) + js * 8 + (n & 7);
    bias0[ntl] = p.bih0[ng] + p.bhh0[ng];
    bias1[ntl] = p.bih1[ng] + p.bhh1[ng];
  }
  float wpj = p.wproj[j];
  float bpj = p.bproj[0];

  float c0r[2][2], c1r[2][2];
#pragma unroll
  for (int mtl = 0; mtl < 2; mtl++)
#pragma unroll
    for (int q = 0; q < 2; q++) {
      int row = L.mb0 + mtl * 16 + L.grp * 4 + L.hlf * 2 + q;
      c0r[mtl][q] = p.c0[row * 512 + j];
      c1r[mtl][q] = p.c0[524288 + row * 512 + j];
    }

  u32* flagc = p.flags + chunk * 64;
  const char* wA1_0 = lds + LDS_WA1 + L.pp * WSTRIDE + L.grp * 16;
  const char* wA1_1 = lds + LDS_WA1 + (16 + L.pp) * WSTRIDE + L.grp * 16;
  const char* wA0_0 = lds + LDS_WA0 + L.pp * WSTRIDE + L.grp * 16;
  const char* wA0_1 = lds + LDS_WA0 + (16 + L.pp) * WSTRIDE + L.grp * 16;
  const char* wB1_0 = lds + LDS_WB1 + L.pp * WSTRIDE + L.grp * 16;
  const char* wB1_1 = lds + LDS_WB1 + (16 + L.pp) * WSTRIDE + L.grp * 16;
  const char* wBU_0 = lds + LDS_WBU + L.pp * WSTRIDE + L.grp * 16;
  const char* wBU_1 = lds + LDS_WBU + (16 + L.pp) * WSTRIDE + L.grp * 16;
  const char* w0c_0 = lds + LDS_W0C + L.pp * 64 + L.grp * 16;
  const char* w0c_1 = lds + LDS_W0C + (16 + L.pp) * 64 + L.grp * 16;

  // consume OWN quarter first: its 16 producers are like-scheduled; foreign
  // quarters get 1-3 consume-groups of slack to absorb skew.
  const int rot = (js >> 4) & 3;
  const int q0 = (rot + 0) & 3, q1 = (rot + 1) & 3;
  const int q2 = (rot + 2) & 3, q3 = (rot + 3) & 3;
  const int g0 = q0 * 4096, g1 = q1 * 4096, g2 = q2 * 4096, g3 = q3 * 4096;
  const int o0 = g0 >> 4, o1 = g1 >> 4, o2 = g2 >> 4, o3 = g3 >> 4;

  __syncthreads();

  f4 accP[4] = {{0,0,0,0},{0,0,0,0},{0,0,0,0},{0,0,0,0}};   // gates0 accum
  f4 accQ[4] = {{0,0,0,0},{0,0,0,0},{0,0,0,0},{0,0,0,0}};   // gates1 accum

  // ===== prologue: gates0(0) = Whh0 h0(-1) + chunk0(y0) ; carry Whh1 h1(-1) =====
  gemmK512_2(p.h0u + 131072, tb0, tb1, wA0_0, wA0_1, accP);
  {
    s8 a0 = {0,0,0,0,0,0,0,0}, a1 = {0,0,0,0,0,0,0,0};
    if (L.grp < 2) {
      const char* xb = (const char*)p.xe;   // t = 0
      a0 = *(const s8*)(xb + (L.mb0 + L.pp) * 32 + L.grp * 16);
      a1 = *(const s8*)(xb + (L.mb0 + 16 + L.pp) * 32 + L.grp * 16);
      if (L.grp == 0) {
        a0[0] = f2bf(bf2f(a0[0]) + yrow[wid * 32 + L.pp]);
        a1[0] = f2bf(bf2f(a1[0]) + yrow[wid * 32 + 16 + L.pp]);
      }
    }
    s8 b0 = *(const s8*)(w0c_0);
    s8 b1 = *(const s8*)(w0c_1);
    accP[0] = MFMA_(a0, b0, accP[0]);
    accP[1] = MFMA_(a0, b1, accP[1]);
    accP[2] = MFMA_(a1, b0, accP[2]);
    accP[3] = MFMA_(a1, b1, accP[3]);
  }
  {
    float hd[2][2];
    cell_update(accP, bias0, c0r, hst, lbase, L, hd);
  }
  gemmK512_2(p.h1u + 131072, tb0, tb1, wB1_0, wB1_1, accQ);  // Whh1 h1(-1) carry
  __syncthreads();
  if (tid < 256) {
    const u64* src = (const u64*)&hst[tid * 8];
    u64* dst = p.h0u + pst;   // slot 0 = h0(0)
    ast(dst, src[0]);
    ast(dst + 1, src[1]);
  }
  arrive(flagc, js, tid, 1u);
#pragma unroll
  for (int q = 0; q < 4; q++) accP[q] = (f4){0, 0, 0, 0};

  v4 A0, A1, A2, A3, A4, A5, A6, A7;
  v4 C0, C1, C2, C3, C4, C5, C6, C7;

  for (int t = 0; t < NSTEPS; t++) {
    // ===== phase A: read h0(t); gates1(t) += Wih1 h0 ; gates0(t+1) += Whh0 h0 =====
    {
      const u32 tg = (u32)(2 * t + 1);
      const char* hb = (const char*)p.h0u + (size_t)(t & 1) * 1048576;
      const char* pa0 = hb + aoff0;
      const char* pa1 = hb + aoff1;
      qwait(flagc, q0, tg, lane);
      IS8(A0,A1,A2,A3,A4,A5,A6,A7, pa0 + g0, pa1 + g0);
      qwait(flagc, q1, tg, lane);
      IS8(C0,C1,C2,C3,C4,C5,C6,C7, pa0 + g1, pa1 + g1);
      WAITV(8);
      cons_dual8(A0,A1,A2,A3,A4,A5,A6,A7, wA1_0+o0, wA1_1+o0, wA0_0+o0, wA0_1+o0, accQ, accP);
      qwait(flagc, q2, tg, lane);
      IS8(A0,A1,A2,A3,A4,A5,A6,A7, pa0 + g2, pa1 + g2);
      WAITV(8);
      cons_dual8(C0,C1,C2,C3,C4,C5,C6,C7, wA1_0+o1, wA1_1+o1, wA0_0+o1, wA0_1+o1, accQ, accP);
      qwait(flagc, q3, tg, lane);
      IS8(C0,C1,C2,C3,C4,C5,C6,C7, pa0 + g3, pa1 + g3);
      WAITV(8);
      cons_dual8(A0,A1,A2,A3,A4,A5,A6,A7, wA1_0+o2, wA1_1+o2, wA0_0+o2, wA0_1+o2, accQ, accP);
      WAITV(0);
      cons_dual8(C0,C1,C2,C3,C4,C5,C6,C7, wA1_0+o3, wA1_1+o3, wA0_0+o3, wA0_1+o3, accQ, accP);

      float hval[2][2];
      cell_update(accQ, bias1, c1r, hst, lbase, L, hval);
      // per-wave EARLY store of own 32 rows (wave-local hst; no block sync needed)
      WAITLGKM();
      if (lane < 32) {
        int rl = lbase + lane;
        const u64* src = (const u64*)&hst[rl * 8];
        u64* dst = p.h1u + (size_t)(t & 1) * 131072
                 + pwb + (rl >> 4) * 2048 + (rl & 15) * 2;
        ast(dst, src[0]);
        ast(dst + 1, src[1]);
      }
      // proj partials -> ypart[js][row]: paired 8B stores tiling exact 64B lines
      {
        float py[2][2];
#pragma unroll
        for (int mtl = 0; mtl < 2; mtl++)
#pragma unroll
          for (int q = 0; q < 2; q++) {
            float s = hval[mtl][q] * wpj;
            s += __shfl_xor(s, 1);
            s += __shfl_xor(s, 2);
            s += __shfl_xor(s, 4);
            py[mtl][q] = s;
          }
        if (L.jl == 0) {
#pragma unroll
          for (int mtl = 0; mtl < 2; mtl++) {
            int row = L.mb0 + mtl * 16 + L.grp * 4 + L.hlf * 2;
            f2u u; u.f[0] = py[mtl][0]; u.f[1] = py[mtl][1];
            ast((u64*)((char*)p.ypart + (size_t)js * 4096 + (size_t)row * 4), u.q);
          }
        }
      }
      arrive(flagc, js, tid, tg + 1);
#pragma unroll
      for (int q = 0; q < 4; q++) accQ[q] = (f4){0, 0, 0, 0};
    }

    // ===== phase B: read h1(t); gates1(t+1) += Whh1 h1 ; gates0(t+1) += U h1 =====
    {
      const u32 tg = (u32)(2 * t + 2);
      const char* hb = (const char*)p.h1u + (size_t)(t & 1) * 1048576;
      const char* pb0 = hb + aoff0;
      const char* pb1 = hb + aoff1;
      qwait(flagc, q0, tg, lane);
      IS8(A0,A1,A2,A3,A4,A5,A6,A7, pb0 + g0, pb1 + g0);
      qwait(flagc, q1, tg, lane);
      IS8(C0,C1,C2,C3,C4,C5,C6,C7, pb0 + g1, pb1 + g1);
      WAITV(8);
      cons_dual8(A0,A1,A2,A3,A4,A5,A6,A7, wB1_0+o0, wB1_1+o0, wBU_0+o0, wBU_1+o0, accQ, accP);
      qwait(flagc, q2, tg, lane);
      IS8(A0,A1,A2,A3,A4,A5,A6,A7, pb0 + g2, pb1 + g2);
      WAITV(8);
      cons_dual8(C0,C1,C2,C3,C4,C5,C6,C7, wB1_0+o1, wB1_1+o1, wBU_0+o1, wBU_1+o1, accQ, accP);
      qwait(flagc, q3, tg, lane);   // after this, ALL 64 producers of A(t) arrived
      IS8(C0,C1,C2,C3,C4,C5,C6,C7, pb0 + g3, pb1 + g3);
      WAITV(8);
      cons_dual8(A0,A1,A2,A3,A4,A5,A6,A7, wB1_0+o2, wB1_1+o2, wBU_0+o2, wBU_1+o2, accQ, accP);
      WAITV(0);
      cons_dual8(C0,C1,C2,C3,C4,C5,C6,C7, wB1_0+o3, wB1_1+o3, wBU_0+o3, wBU_1+o3, accQ, accP);

      // chunk0 of gates0(t+1): exo+z(+bproj) const part (y folded into U + xe slot0)
      {
        int tn = (t < 63) ? t + 1 : 63;
        s8 a0 = {0,0,0,0,0,0,0,0}, a1 = {0,0,0,0,0,0,0,0};
        if (L.grp < 2) {
          const char* xb = (const char*)p.xe + (size_t)tn * 32768;
          a0 = *(const s8*)(xb + (L.mb0 + L.pp) * 32 + L.grp * 16);
          a1 = *(const s8*)(xb + (L.mb0 + 16 + L.pp) * 32 + L.grp * 16);
        }
        s8 b0 = *(const s8*)(w0c_0);
        s8 b1 = *(const s8*)(w0c_1);
        accP[0] = MFMA_(a0, b0, accP[0]);
        accP[1] = MFMA_(a0, b1, accP[1]);
        accP[2] = MFMA_(a1, b0, accP[2]);
        accP[3] = MFMA_(a1, b1, accP[3]);
      }
      float hd[2][2];
      cell_update(accP, bias0, c0r, hst, lbase, L, hd);
      // per-wave EARLY store of own 32 rows
      WAITLGKM();
      if (lane < 32) {
        int rl = lbase + lane;
        const u64* src = (const u64*)&hst[rl * 8];
        u64* dst = p.h0u + (size_t)((t + 1) & 1) * 131072
                 + pwb + (rl >> 4) * 2048 + (rl & 15) * 2;
        ast(dst, src[0]);
        ast(dst + 1, src[1]);
      }
      // y-reduce of step t, MOVED to phase end: output-only (U-trick), so its
      // WAITV(0) over-drain on wave 0 now overlaps the other waves' join in
      // arrive instead of stalling the consume pipeline. Gated by qwait q3
      // above (all 64 ypart producers arrived); ypart rewrite happens in
      // phase A of t+1, gated on THIS phase's arrivals (incl. wave-0 drain).
      if (tid < 64) {
        v4 Yv;
        const char* yq = (const char*)p.ypart + (size_t)lane * 4096
                       + (size_t)(chunk * 256 + js * 4) * 4;
        LOADX4(Yv, yq, 0);
        WAITV(0);
        vf4 w; w.u = Yv;
        float s0 = w.f[0], s1 = w.f[1], s2 = w.f[2], s3 = w.f[3];
#pragma unroll
        for (int m = 1; m < 64; m <<= 1) {
          s0 += __shfl_xor(s0, m);
          s1 += __shfl_xor(s1, m);
          s2 += __shfl_xor(s2, m);
          s3 += __shfl_xor(s3, m);
        }
        if (lane == 0) {
          int rb = chunk * 256 + js * 4;
          p.out[(rb + 0) * 64 + t] = s0 + bpj;
          p.out[(rb + 1) * 64 + t] = s1 + bpj;
          p.out[(rb + 2) * 64 + t] = s2 + bpj;
          p.out[(rb + 3) * 64 + t] = s3 + bpj;
        }
      }
      arrive(flagc, js, tid, tg + 1);
#pragma unroll
      for (int q = 0; q < 4; q++) accP[q] = (f4){0, 0, 0, 0};
    }
  }
}

extern "C" void kernel_launch(void* const* d_in, const int* in_sizes, int n_in,
                              void* d_out, int out_size, void* d_ws, size_t ws_size,
                              hipStream_t stream) {
  const float* y0   = (const float*)d_in[0];
  const float* xf   = (const float*)d_in[1];
  const float* h0   = (const float*)d_in[2];
  const float* c0   = (const float*)d_in[3];
  const float* z    = (const float*)d_in[4];
  const float* Wih0 = (const float*)d_in[5];
  const float* Whh0 = (const float*)d_in[6];
  const float* bih0 = (const float*)d_in[7];
  const float* bhh0 = (const float*)d_in[8];
  const float* Wih1 = (const float*)d_in[9];
  const float* Whh1 = (const float*)d_in[10];
  const float* bih1 = (const float*)d_in[11];
  const float* bhh1 = (const float*)d_in[12];
  const float* Wpr  = (const float*)d_in[13];
  const float* bpr  = (const float*)d_in[14];
  const float* Wz   = (const float*)d_in[15];
  const float* bz   = (const float*)d_in[16];

  if (ws_size < WS_NEEDED) return;
  char* ws = (char*)d_ws;
  u16* xe    = (u16*)(ws + WS_XE);
  u16* w0c   = (u16*)(ws + WS_W0C);
  u16* wih1  = (u16*)(ws + WS_WIH1);
  u16* whh0  = (u16*)(ws + WS_WHH0);
  u16* whh1  = (u16*)(ws + WS_WHH1);
  u16* up    = (u16*)(ws + WS_UP);
  u64* h0u   = (u64*)(ws + WS_H0S);
  u64* h1u   = (u64*)(ws + WS_H1S);
  float* ypart = (float*)(ws + WS_YPART);
  u32* flags = (u32*)(ws + WS_FLAGS);

  prep_pack<<<1024, 256, 0, stream>>>(Wih0, Whh0, Wih1, Whh1, Wpr,
                                      w0c, wih1, whh0, whh1, up);
  prep_xe<<<256, 256, 0, stream>>>(xf, z, Wz, bz, bpr, xe);
  prep_state<<<2048, 256, 0, stream>>>(h0, (u16*)h0u, (u16*)h1u, flags);

  MainParams prm;
  prm.y0 = y0; prm.c0 = c0;
  prm.bih0 = bih0; prm.bhh0 = bhh0; prm.bih1 = bih1; prm.bhh1 = bhh1;
  prm.wproj = Wpr; prm.bproj = bpr;
  prm.xe = xe; prm.w0c = w0c; prm.wih1 = wih1; prm.whh0 = whh0;
  prm.whh1 = whh1; prm.up = up;
  prm.h0u = h0u; prm.h1u = h1u; prm.ypart = ypart; prm.flags = flags;
  prm.out = (float*)d_out;

  hipFuncSetAttribute((const void*)lstm_main, hipFuncAttributeMaxDynamicSharedMemorySize, LDS_TOTAL);
  void* args[] = { &prm };
  hipLaunchCooperativeKernel((void*)lstm_main, dim3(256), dim3(512), args, LDS_TOTAL, stream);
}